// Round 1
// baseline (12282.099 us; speedup 1.0000x reference)
//
#include <hip/hip_runtime.h>
#include <math.h>

#define D_MODEL 256
#define NHEADS 4
#define DK 64
#define NLAYERS 4
#define FFDIM 1024
#define BB 16
#define SS 2048
#define NTOK (BB*SS)

// ---------------------------------------------------------------- embedding + posenc
__global__ void embed_kernel(const int* __restrict__ ids, const float* __restrict__ emb,
                             float* __restrict__ x) {
    int idx = blockIdx.x * 256 + threadIdx.x;   // over NTOK*D_MODEL
    int tok = idx >> 8;
    int d   = idx & 255;
    int s   = tok & (SS - 1);
    int id  = ids[tok];
    float e = emb[id * D_MODEL + d] * 16.0f;     // sqrt(256)
    float i2 = (float)((d >> 1) << 1);           // 2*(d/2)
    float div = expf(i2 * (-9.210340371976184f / 256.0f));  // -ln(10000)/256
    float ang = (float)s * div;
    float pe = (d & 1) ? cosf(ang) : sinf(ang);
    x[idx] = e + pe;
}

// ---------------------------------------------------------------- fp32 tiled GEMM: C = A@W + bias (opt relu)
// A: N x K row-major, W: K x M row-major, C: N x M. 64x64 tile, BK=16, 256 thr, 4x4 micro.
template<int RELU>
__global__ void gemm_kernel(const float* __restrict__ A, const float* __restrict__ W,
                            const float* __restrict__ bias, float* __restrict__ C,
                            int N, int K, int M) {
    __shared__ float As[16][65];   // [kk][row]
    __shared__ float Bs[16][65];   // [kk][col]
    int tid = threadIdx.x;
    int tx = tid & 15, ty = tid >> 4;
    int rowBase = blockIdx.x * 64;
    int colBase = blockIdx.y * 64;

    float acc[4][4] = {};

    for (int kt = 0; kt < K; kt += 16) {
        #pragma unroll
        for (int u = 0; u < 4; ++u) {
            int idx = tid + u * 256;          // 0..1023 over 64x16 A-tile
            int r = idx >> 4, c = idx & 15;
            As[c][r] = A[(size_t)(rowBase + r) * K + kt + c];
        }
        #pragma unroll
        for (int u = 0; u < 4; ++u) {
            int idx = tid + u * 256;          // 0..1023 over 16x64 W-tile
            int kk = idx >> 6, m = idx & 63;
            Bs[kk][m] = W[(size_t)(kt + kk) * M + colBase + m];
        }
        __syncthreads();
        #pragma unroll
        for (int kk = 0; kk < 16; ++kk) {
            float a0 = As[kk][ty*4+0], a1 = As[kk][ty*4+1];
            float a2 = As[kk][ty*4+2], a3 = As[kk][ty*4+3];
            float b0 = Bs[kk][tx*4+0], b1 = Bs[kk][tx*4+1];
            float b2 = Bs[kk][tx*4+2], b3 = Bs[kk][tx*4+3];
            acc[0][0] += a0*b0; acc[0][1] += a0*b1; acc[0][2] += a0*b2; acc[0][3] += a0*b3;
            acc[1][0] += a1*b0; acc[1][1] += a1*b1; acc[1][2] += a1*b2; acc[1][3] += a1*b3;
            acc[2][0] += a2*b0; acc[2][1] += a2*b1; acc[2][2] += a2*b2; acc[2][3] += a2*b3;
            acc[3][0] += a3*b0; acc[3][1] += a3*b1; acc[3][2] += a3*b2; acc[3][3] += a3*b3;
        }
        __syncthreads();
    }

    #pragma unroll
    for (int i = 0; i < 4; ++i) {
        #pragma unroll
        for (int j = 0; j < 4; ++j) {
            float v = acc[i][j] + bias[colBase + tx*4 + j];
            if (RELU) v = fmaxf(v, 0.0f);
            C[(size_t)(rowBase + ty*4 + i) * M + colBase + tx*4 + j] = v;
        }
    }
}

// ---------------------------------------------------------------- flash attention (fp32)
// grid: (SS/64, NHEADS, BB); block 256. Online softmax, key-pad mask.
__global__ void flash_kernel(const float* __restrict__ q, const float* __restrict__ k,
                             const float* __restrict__ v, const int* __restrict__ ids,
                             float* __restrict__ out) {
    __shared__ float q_s[64][65];
    __shared__ float k_s[64][65];
    __shared__ float v_s[64][65];
    __shared__ float p_s[64][65];
    __shared__ float madd[64];

    int qb = blockIdx.x, h = blockIdx.y, b = blockIdx.z;
    int tid = threadIdx.x;
    int tx = tid & 15, ty = tid >> 4;

    const float* qp = q + (size_t)b * SS * D_MODEL + h * DK;
    const float* kp = k + (size_t)b * SS * D_MODEL + h * DK;
    const float* vp = v + (size_t)b * SS * D_MODEL + h * DK;

    #pragma unroll
    for (int u = 0; u < 16; ++u) {
        int idx = tid + u * 256;            // 64x64 Q tile
        int r = idx >> 6, c = idx & 63;
        q_s[r][c] = qp[(size_t)(qb*64 + r) * D_MODEL + c];
    }

    float m_i[4], l_i[4], acc[4][4];
    #pragma unroll
    for (int i = 0; i < 4; ++i) {
        m_i[i] = -1e30f; l_i[i] = 0.0f;
        #pragma unroll
        for (int j = 0; j < 4; ++j) acc[i][j] = 0.0f;
    }

    for (int kb = 0; kb < SS/64; ++kb) {
        __syncthreads();   // prev iter done reading k_s/v_s/p_s
        #pragma unroll
        for (int u = 0; u < 16; ++u) {
            int idx = tid + u * 256;
            int r = idx >> 6, c = idx & 63;
            k_s[r][c] = kp[(size_t)(kb*64 + r) * D_MODEL + c];
            v_s[r][c] = vp[(size_t)(kb*64 + r) * D_MODEL + c];
        }
        if (tid < 64) {
            int kid = ids[b*SS + kb*64 + tid];
            madd[tid] = (kid != 0) ? 0.0f : -1e30f;
        }
        __syncthreads();

        float sv[4][4] = {};
        #pragma unroll 16
        for (int kk = 0; kk < 64; ++kk) {
            float a0 = q_s[ty*4+0][kk], a1 = q_s[ty*4+1][kk];
            float a2 = q_s[ty*4+2][kk], a3 = q_s[ty*4+3][kk];
            float b0 = k_s[tx*4+0][kk], b1 = k_s[tx*4+1][kk];
            float b2 = k_s[tx*4+2][kk], b3 = k_s[tx*4+3][kk];
            sv[0][0] += a0*b0; sv[0][1] += a0*b1; sv[0][2] += a0*b2; sv[0][3] += a0*b3;
            sv[1][0] += a1*b0; sv[1][1] += a1*b1; sv[1][2] += a1*b2; sv[1][3] += a1*b3;
            sv[2][0] += a2*b0; sv[2][1] += a2*b1; sv[2][2] += a2*b2; sv[2][3] += a2*b3;
            sv[3][0] += a3*b0; sv[3][1] += a3*b1; sv[3][2] += a3*b2; sv[3][3] += a3*b3;
        }

        #pragma unroll
        for (int i = 0; i < 4; ++i) {
            #pragma unroll
            for (int j = 0; j < 4; ++j)
                sv[i][j] = sv[i][j] * 0.125f + madd[tx*4 + j];

            float tmax = fmaxf(fmaxf(sv[i][0], sv[i][1]), fmaxf(sv[i][2], sv[i][3]));
            #pragma unroll
            for (int off = 1; off < 16; off <<= 1)
                tmax = fmaxf(tmax, __shfl_xor(tmax, off));
            float mnew = fmaxf(m_i[i], tmax);
            float alpha = expf(m_i[i] - mnew);
            float rsum = 0.0f;
            #pragma unroll
            for (int j = 0; j < 4; ++j) {
                float p = (sv[i][j] < -5e29f) ? 0.0f : expf(sv[i][j] - mnew);
                sv[i][j] = p;
                rsum += p;
            }
            #pragma unroll
            for (int off = 1; off < 16; off <<= 1)
                rsum += __shfl_xor(rsum, off);
            l_i[i] = l_i[i] * alpha + rsum;
            m_i[i] = mnew;
            #pragma unroll
            for (int j = 0; j < 4; ++j) acc[i][j] *= alpha;
            #pragma unroll
            for (int j = 0; j < 4; ++j) p_s[ty*4+i][tx*4+j] = sv[i][j];
        }
        __syncthreads();

        #pragma unroll 16
        for (int kk = 0; kk < 64; ++kk) {
            float p0 = p_s[ty*4+0][kk], p1 = p_s[ty*4+1][kk];
            float p2 = p_s[ty*4+2][kk], p3 = p_s[ty*4+3][kk];
            float w0 = v_s[kk][tx*4+0], w1 = v_s[kk][tx*4+1];
            float w2 = v_s[kk][tx*4+2], w3 = v_s[kk][tx*4+3];
            acc[0][0] += p0*w0; acc[0][1] += p0*w1; acc[0][2] += p0*w2; acc[0][3] += p0*w3;
            acc[1][0] += p1*w0; acc[1][1] += p1*w1; acc[1][2] += p1*w2; acc[1][3] += p1*w3;
            acc[2][0] += p2*w0; acc[2][1] += p2*w1; acc[2][2] += p2*w2; acc[2][3] += p2*w3;
            acc[3][0] += p3*w0; acc[3][1] += p3*w1; acc[3][2] += p3*w2; acc[3][3] += p3*w3;
        }
    }

    #pragma unroll
    for (int i = 0; i < 4; ++i) {
        float inv = 1.0f / l_i[i];
        #pragma unroll
        for (int j = 0; j < 4; ++j)
            out[(size_t)(b*SS + qb*64 + ty*4 + i) * D_MODEL + h*64 + tx*4 + j] = acc[i][j] * inv;
    }
}

// ---------------------------------------------------------------- fused residual + LN (row=256)
// block 256 = 4 waves, one row per wave. out = LN(resid + y) * g + be  (y already has bias)
__global__ void ln_kernel(const float* __restrict__ resid, const float* __restrict__ y,
                          const float* __restrict__ g, const float* __restrict__ be,
                          float* __restrict__ out) {
    int wave = threadIdx.x >> 6;
    int lane = threadIdx.x & 63;
    int row = blockIdx.x * 4 + wave;
    size_t base = (size_t)row * D_MODEL + lane * 4;

    float4 a = *(const float4*)(resid + base);
    float4 bv = *(const float4*)(y + base);
    float v0 = a.x + bv.x, v1 = a.y + bv.y, v2 = a.z + bv.z, v3 = a.w + bv.w;

    float sum = v0 + v1 + v2 + v3;
    #pragma unroll
    for (int off = 1; off < 64; off <<= 1) sum += __shfl_xor(sum, off);
    float mu = sum * (1.0f / 256.0f);

    float d0 = v0 - mu, d1 = v1 - mu, d2 = v2 - mu, d3 = v3 - mu;
    float vs = d0*d0 + d1*d1 + d2*d2 + d3*d3;
    #pragma unroll
    for (int off = 1; off < 64; off <<= 1) vs += __shfl_xor(vs, off);
    float rstd = rsqrtf(vs * (1.0f / 256.0f) + 1e-5f);

    int c = lane * 4;
    float4 gv = *(const float4*)(g + c);
    float4 bev = *(const float4*)(be + c);
    float4 o;
    o.x = d0 * rstd * gv.x + bev.x;
    o.y = d1 * rstd * gv.y + bev.y;
    o.z = d2 * rstd * gv.z + bev.z;
    o.w = d3 * rstd * gv.w + bev.w;
    *(float4*)(out + base) = o;
}

// ---------------------------------------------------------------- masked mean pool
__global__ void pool_kernel(const float* __restrict__ x, const int* __restrict__ ids,
                            float* __restrict__ pooled) {
    int b = blockIdx.x;
    int d = threadIdx.x;
    float acc = 0.0f;
    int cnt = 0;
    for (int s = 0; s < SS; ++s) {
        int id = ids[b*SS + s];
        if (id != 0) { acc += x[(size_t)(b*SS + s) * D_MODEL + d]; cnt++; }
    }
    pooled[b * D_MODEL + d] = acc / fmaxf((float)cnt, 1e-9f);
}

// ---------------------------------------------------------------- classifier 16x10
__global__ void cls_kernel(const float* __restrict__ pooled, const float* __restrict__ Wc,
                           const float* __restrict__ bc, float* __restrict__ outp) {
    int t = threadIdx.x;
    if (t >= BB * 10) return;
    int b = t / 10, c = t % 10;
    float acc = bc[c];
    for (int d = 0; d < D_MODEL; ++d)
        acc += pooled[b * D_MODEL + d] * Wc[d * 10 + c];
    outp[t] = acc;
}

// ---------------------------------------------------------------- launch
extern "C" void kernel_launch(void* const* d_in, const int* in_sizes, int n_in,
                              void* d_out, int out_size, void* d_ws, size_t ws_size,
                              hipStream_t stream) {
    const int*   ids = (const int*)  d_in[0];
    const float* emb = (const float*)d_in[1];
    const float* Wq  = (const float*)d_in[2];
    const float* bq  = (const float*)d_in[3];
    const float* Wk  = (const float*)d_in[4];
    const float* bk  = (const float*)d_in[5];
    const float* Wv  = (const float*)d_in[6];
    const float* bv  = (const float*)d_in[7];
    const float* Wo  = (const float*)d_in[8];
    const float* bo  = (const float*)d_in[9];
    const float* g1  = (const float*)d_in[10];
    const float* be1 = (const float*)d_in[11];
    const float* W1  = (const float*)d_in[12];
    const float* b1  = (const float*)d_in[13];
    const float* W2  = (const float*)d_in[14];
    const float* b2  = (const float*)d_in[15];
    const float* g2  = (const float*)d_in[16];
    const float* be2 = (const float*)d_in[17];
    const float* Wc  = (const float*)d_in[18];
    const float* bc  = (const float*)d_in[19];
    float* outp = (float*)d_out;

    float* ws = (float*)d_ws;
    const size_t TD = (size_t)NTOK * D_MODEL;   // 8.39M floats
    float* x  = ws;
    float* qb = ws + TD;
    float* kb = ws + 2*TD;
    float* vb = ws + 3*TD;
    float* t0 = ws + 4*TD;
    float* t1 = ws + 5*TD;
    float* hh = qb;          // FFN hidden: NTOK*1024 floats = 4*TD, spans q..t0 (dead there)

    embed_kernel<<<NTOK, 256, 0, stream>>>(ids, emb, x);

    dim3 gProj(NTOK/64, D_MODEL/64);     // (512, 4)
    dim3 gFF1 (NTOK/64, FFDIM/64);       // (512, 16)
    dim3 gAttn(SS/64, NHEADS, BB);       // (32, 4, 16)

    for (int l = 0; l < NLAYERS; ++l) {
        const float* Wq_l = Wq + (size_t)l * D_MODEL * D_MODEL;
        const float* Wk_l = Wk + (size_t)l * D_MODEL * D_MODEL;
        const float* Wv_l = Wv + (size_t)l * D_MODEL * D_MODEL;
        const float* Wo_l = Wo + (size_t)l * D_MODEL * D_MODEL;
        const float* W1_l = W1 + (size_t)l * D_MODEL * FFDIM;
        const float* W2_l = W2 + (size_t)l * FFDIM * D_MODEL;

        gemm_kernel<0><<<gProj, 256, 0, stream>>>(x, Wq_l, bq + l*D_MODEL, qb, NTOK, D_MODEL, D_MODEL);
        gemm_kernel<0><<<gProj, 256, 0, stream>>>(x, Wk_l, bk + l*D_MODEL, kb, NTOK, D_MODEL, D_MODEL);
        gemm_kernel<0><<<gProj, 256, 0, stream>>>(x, Wv_l, bv + l*D_MODEL, vb, NTOK, D_MODEL, D_MODEL);
        flash_kernel<<<gAttn, 256, 0, stream>>>(qb, kb, vb, ids, t0);
        gemm_kernel<0><<<gProj, 256, 0, stream>>>(t0, Wo_l, bo + l*D_MODEL, t1, NTOK, D_MODEL, D_MODEL);
        ln_kernel<<<NTOK/4, 256, 0, stream>>>(x, t1, g1 + l*D_MODEL, be1 + l*D_MODEL, x);

        gemm_kernel<1><<<gFF1, 256, 0, stream>>>(x, W1_l, b1 + l*FFDIM, hh, NTOK, D_MODEL, FFDIM);
        gemm_kernel<0><<<gProj, 256, 0, stream>>>(hh, W2_l, b2 + l*D_MODEL, t1, NTOK, FFDIM, D_MODEL);
        ln_kernel<<<NTOK/4, 256, 0, stream>>>(x, t1, g2 + l*D_MODEL, be2 + l*D_MODEL, x);
    }

    pool_kernel<<<BB, 256, 0, stream>>>(x, ids, t0);
    cls_kernel<<<1, 256, 0, stream>>>(t0, Wc, bc, outp);
}

// Round 2
// 5733.440 us; speedup vs baseline: 2.1422x; 2.1422x over previous
//
#include <hip/hip_runtime.h>
#include <math.h>

#define D_MODEL 256
#define NHEADS 4
#define DK 64
#define NLAYERS 4
#define FFDIM 1024
#define BB 16
#define SS 2048
#define NTOK (BB*SS)

typedef __attribute__((ext_vector_type(8))) short bf16x8;
typedef __attribute__((ext_vector_type(4))) short s16x4;
typedef __attribute__((ext_vector_type(4))) float f32x4;

__device__ __forceinline__ short f2bf(float f) {
    unsigned u = __float_as_uint(f);
    unsigned r = (u + 0x7fffu + ((u >> 16) & 1u)) >> 16;
    return (short)r;
}

// ---------------------------------------------------------------- embedding + posenc
__global__ void embed_kernel(const int* __restrict__ ids, const float* __restrict__ emb,
                             float* __restrict__ x) {
    int idx = blockIdx.x * 256 + threadIdx.x;   // over NTOK*D_MODEL
    int tok = idx >> 8;
    int d   = idx & 255;
    int s   = tok & (SS - 1);
    int id  = ids[tok];
    float e = emb[id * D_MODEL + d] * 16.0f;     // sqrt(256)
    float i2 = (float)((d >> 1) << 1);           // 2*(d/2)
    float div = expf(i2 * (-9.210340371976184f / 256.0f));  // -ln(10000)/256
    float ang = (float)s * div;
    float pe = (d & 1) ? cosf(ang) : sinf(ang);
    x[idx] = e + pe;
}

// ---------------------------------------------------------------- fp32 tiled GEMM: C = A@W + bias (opt relu)
template<int RELU>
__global__ void gemm_kernel(const float* __restrict__ A, const float* __restrict__ W,
                            const float* __restrict__ bias, float* __restrict__ C,
                            int N, int K, int M) {
    __shared__ float As[16][65];   // [kk][row]
    __shared__ float Bs[16][65];   // [kk][col]
    int tid = threadIdx.x;
    int tx = tid & 15, ty = tid >> 4;
    int rowBase = blockIdx.x * 64;
    int colBase = blockIdx.y * 64;

    float acc[4][4] = {};

    for (int kt = 0; kt < K; kt += 16) {
        #pragma unroll
        for (int u = 0; u < 4; ++u) {
            int idx = tid + u * 256;
            int r = idx >> 4, c = idx & 15;
            As[c][r] = A[(size_t)(rowBase + r) * K + kt + c];
        }
        #pragma unroll
        for (int u = 0; u < 4; ++u) {
            int idx = tid + u * 256;
            int kk = idx >> 6, m = idx & 63;
            Bs[kk][m] = W[(size_t)(kt + kk) * M + colBase + m];
        }
        __syncthreads();
        #pragma unroll
        for (int kk = 0; kk < 16; ++kk) {
            float a0 = As[kk][ty*4+0], a1 = As[kk][ty*4+1];
            float a2 = As[kk][ty*4+2], a3 = As[kk][ty*4+3];
            float b0 = Bs[kk][tx*4+0], b1 = Bs[kk][tx*4+1];
            float b2 = Bs[kk][tx*4+2], b3 = Bs[kk][tx*4+3];
            acc[0][0] += a0*b0; acc[0][1] += a0*b1; acc[0][2] += a0*b2; acc[0][3] += a0*b3;
            acc[1][0] += a1*b0; acc[1][1] += a1*b1; acc[1][2] += a1*b2; acc[1][3] += a1*b3;
            acc[2][0] += a2*b0; acc[2][1] += a2*b1; acc[2][2] += a2*b2; acc[2][3] += a2*b3;
            acc[3][0] += a3*b0; acc[3][1] += a3*b1; acc[3][2] += a3*b2; acc[3][3] += a3*b3;
        }
        __syncthreads();
    }

    #pragma unroll
    for (int i = 0; i < 4; ++i) {
        #pragma unroll
        for (int j = 0; j < 4; ++j) {
            float v = acc[i][j] + bias[colBase + tx*4 + j];
            if (RELU) v = fmaxf(v, 0.0f);
            C[(size_t)(rowBase + ty*4 + i) * M + colBase + tx*4 + j] = v;
        }
    }
}

// ---------------------------------------------------------------- bf16 MFMA flash attention
// grid: (SS/64, NHEADS, BB); block 256 = 4 waves. Wave w handles 16 q-rows.
// Layouts: A-frag lane l holds row l%16, k = 8*(l/16)+j. B-frag lane l holds col l%16.
// C/D: col = l&15, row = (l>>4)*4 + reg.
__global__ __launch_bounds__(256) void flash_mfma_kernel(
        const float* __restrict__ q, const float* __restrict__ k,
        const float* __restrict__ v, const int* __restrict__ ids,
        float* __restrict__ out) {
    __shared__ short k_s[64][72];        // [key][d]
    __shared__ short vt_s[64][72];       // [d][key]  (transposed V)
    __shared__ short p_s[4][16][72];     // per-wave P buffer [q][key]
    __shared__ float madd_s[64];

    int qb = blockIdx.x, h = blockIdx.y, b = blockIdx.z;
    int tid = threadIdx.x;
    int w = tid >> 6, lane = tid & 63;
    int lr = lane & 15, lg = lane >> 4;

    const float* qp = q + (size_t)b * SS * D_MODEL + h * DK;
    const float* kp = k + (size_t)b * SS * D_MODEL + h * DK;
    const float* vp = v + (size_t)b * SS * D_MODEL + h * DK;

    // Q fragments (held for whole kernel): Q[qrow][d], d = lg*8 + ks*32 + j
    int qrow = qb*64 + w*16 + lr;
    bf16x8 qf[2];
    #pragma unroll
    for (int ks = 0; ks < 2; ++ks) {
        const float* src = qp + (size_t)qrow * D_MODEL + lg*8 + ks*32;
        #pragma unroll
        for (int j = 0; j < 8; ++j) qf[ks][j] = f2bf(src[j]);
    }

    f32x4 o[4];
    float m_i[4], l_i[4];
    #pragma unroll
    for (int r = 0; r < 4; ++r) {
        m_i[r] = -1e30f; l_i[r] = 0.0f;
        o[r][0] = 0.f; o[r][1] = 0.f; o[r][2] = 0.f; o[r][3] = 0.f;
    }

    for (int kb = 0; kb < SS/64; ++kb) {
        __syncthreads();
        // stage K (row-major) and V (transposed) as bf16
        #pragma unroll
        for (int u = 0; u < 4; ++u) {
            int e = tid + u * 256;
            int r = e >> 4, c4 = (e & 15) * 4;
            const float4 kv = *(const float4*)(kp + (size_t)(kb*64 + r) * D_MODEL + c4);
            s16x4 kw; kw[0]=f2bf(kv.x); kw[1]=f2bf(kv.y); kw[2]=f2bf(kv.z); kw[3]=f2bf(kv.w);
            *(s16x4*)&k_s[r][c4] = kw;
            const float4 vv = *(const float4*)(vp + (size_t)(kb*64 + r) * D_MODEL + c4);
            vt_s[c4  ][r] = f2bf(vv.x);
            vt_s[c4+1][r] = f2bf(vv.y);
            vt_s[c4+2][r] = f2bf(vv.z);
            vt_s[c4+3][r] = f2bf(vv.w);
        }
        if (tid < 64)
            madd_s[tid] = (ids[b*SS + kb*64 + tid] != 0) ? 0.0f : -1e30f;
        __syncthreads();

        float mk[4];
        #pragma unroll
        for (int t = 0; t < 4; ++t) mk[t] = madd_s[lr + 16*t];

        // S = Q @ K^T : 4 16x16 tiles over keys
        f32x4 s[4];
        #pragma unroll
        for (int t = 0; t < 4; ++t) {
            bf16x8 kf0 = *(const bf16x8*)&k_s[t*16 + lr][lg*8];
            bf16x8 kf1 = *(const bf16x8*)&k_s[t*16 + lr][lg*8 + 32];
            f32x4 acc = {0.f, 0.f, 0.f, 0.f};
            acc = __builtin_amdgcn_mfma_f32_16x16x32_bf16(qf[0], kf0, acc, 0, 0, 0);
            acc = __builtin_amdgcn_mfma_f32_16x16x32_bf16(qf[1], kf1, acc, 0, 0, 0);
            s[t] = acc;
        }

        // online softmax: lane owns rows lg*4+r, col lr+16t
        #pragma unroll
        for (int r = 0; r < 4; ++r) {
            float sr[4];
            #pragma unroll
            for (int t = 0; t < 4; ++t) sr[t] = s[t][r] * 0.125f + mk[t];
            float mx = fmaxf(fmaxf(sr[0], sr[1]), fmaxf(sr[2], sr[3]));
            #pragma unroll
            for (int off = 1; off < 16; off <<= 1)
                mx = fmaxf(mx, __shfl_xor(mx, off));
            float mnew = fmaxf(m_i[r], mx);
            float alpha = __expf(m_i[r] - mnew);
            float p[4], rsum = 0.0f;
            #pragma unroll
            for (int t = 0; t < 4; ++t) {
                p[t] = (sr[t] < -5e29f) ? 0.0f : __expf(sr[t] - mnew);
                rsum += p[t];
            }
            #pragma unroll
            for (int off = 1; off < 16; off <<= 1)
                rsum += __shfl_xor(rsum, off);
            l_i[r] = l_i[r] * alpha + rsum;
            m_i[r] = mnew;
            #pragma unroll
            for (int dt = 0; dt < 4; ++dt) o[dt][r] *= alpha;
            #pragma unroll
            for (int t = 0; t < 4; ++t)
                p_s[w][lg*4 + r][lr + 16*t] = f2bf(p[t]);
        }
        // no barrier: p_s is per-wave

        // O += P @ V : A = P rows (from p_s), B = V (from transposed vt_s)
        bf16x8 pa[2];
        #pragma unroll
        for (int ks = 0; ks < 2; ++ks)
            pa[ks] = *(const bf16x8*)&p_s[w][lr][ks*32 + lg*8];
        #pragma unroll
        for (int dt = 0; dt < 4; ++dt) {
            #pragma unroll
            for (int ks = 0; ks < 2; ++ks) {
                bf16x8 vb = *(const bf16x8*)&vt_s[dt*16 + lr][ks*32 + lg*8];
                o[dt] = __builtin_amdgcn_mfma_f32_16x16x32_bf16(pa[ks], vb, o[dt], 0, 0, 0);
            }
        }
    }

    // epilogue
    #pragma unroll
    for (int r = 0; r < 4; ++r) {
        float inv = 1.0f / l_i[r];
        int row = b*SS + qb*64 + w*16 + lg*4 + r;
        #pragma unroll
        for (int dt = 0; dt < 4; ++dt)
            out[(size_t)row * D_MODEL + h*DK + dt*16 + lr] = o[dt][r] * inv;
    }
}

// ---------------------------------------------------------------- fused residual + LN
__global__ void ln_kernel(const float* __restrict__ resid, const float* __restrict__ y,
                          const float* __restrict__ g, const float* __restrict__ be,
                          float* __restrict__ out) {
    int wave = threadIdx.x >> 6;
    int lane = threadIdx.x & 63;
    int row = blockIdx.x * 4 + wave;
    size_t base = (size_t)row * D_MODEL + lane * 4;

    float4 a = *(const float4*)(resid + base);
    float4 bv = *(const float4*)(y + base);
    float v0 = a.x + bv.x, v1 = a.y + bv.y, v2 = a.z + bv.z, v3 = a.w + bv.w;

    float sum = v0 + v1 + v2 + v3;
    #pragma unroll
    for (int off = 1; off < 64; off <<= 1) sum += __shfl_xor(sum, off);
    float mu = sum * (1.0f / 256.0f);

    float d0 = v0 - mu, d1 = v1 - mu, d2 = v2 - mu, d3 = v3 - mu;
    float vs = d0*d0 + d1*d1 + d2*d2 + d3*d3;
    #pragma unroll
    for (int off = 1; off < 64; off <<= 1) vs += __shfl_xor(vs, off);
    float rstd = rsqrtf(vs * (1.0f / 256.0f) + 1e-5f);

    int c = lane * 4;
    float4 gv = *(const float4*)(g + c);
    float4 bev = *(const float4*)(be + c);
    float4 o;
    o.x = d0 * rstd * gv.x + bev.x;
    o.y = d1 * rstd * gv.y + bev.y;
    o.z = d2 * rstd * gv.z + bev.z;
    o.w = d3 * rstd * gv.w + bev.w;
    *(float4*)(out + base) = o;
}

// ---------------------------------------------------------------- masked mean pool (2-stage)
__global__ void pool1_kernel(const float* __restrict__ x, const int* __restrict__ ids,
                             float* __restrict__ partial) {
    int b = blockIdx.x >> 4, chunk = blockIdx.x & 15;
    int d = threadIdx.x;
    float acc = 0.0f;
    int s0 = chunk * 128;
    for (int s = s0; s < s0 + 128; ++s) {
        if (ids[b*SS + s] != 0) acc += x[(size_t)(b*SS + s) * D_MODEL + d];
    }
    partial[(size_t)(b*16 + chunk) * D_MODEL + d] = acc;
}

__global__ void pool2_kernel(const float* __restrict__ partial, const int* __restrict__ ids,
                             float* __restrict__ pooled) {
    int b = blockIdx.x;
    int d = threadIdx.x;
    float acc = 0.0f;
    for (int c = 0; c < 16; ++c) acc += partial[(size_t)(b*16 + c) * D_MODEL + d];
    int cnt = 0;
    for (int s = threadIdx.x; s < SS; s += 256) cnt += (ids[b*SS + s] != 0);
    __shared__ int cs[256];
    cs[threadIdx.x] = cnt;
    __syncthreads();
    for (int off = 128; off > 0; off >>= 1) {
        if (threadIdx.x < off) cs[threadIdx.x] += cs[threadIdx.x + off];
        __syncthreads();
    }
    float total = (float)cs[0];
    pooled[b * D_MODEL + d] = acc / fmaxf(total, 1e-9f);
}

// ---------------------------------------------------------------- classifier 16x10
__global__ void cls_kernel(const float* __restrict__ pooled, const float* __restrict__ Wc,
                           const float* __restrict__ bc, float* __restrict__ outp) {
    int t = threadIdx.x;
    if (t >= BB * 10) return;
    int b = t / 10, c = t % 10;
    float acc = bc[c];
    for (int d = 0; d < D_MODEL; ++d)
        acc += pooled[b * D_MODEL + d] * Wc[d * 10 + c];
    outp[t] = acc;
}

// ---------------------------------------------------------------- launch
extern "C" void kernel_launch(void* const* d_in, const int* in_sizes, int n_in,
                              void* d_out, int out_size, void* d_ws, size_t ws_size,
                              hipStream_t stream) {
    const int*   ids = (const int*)  d_in[0];
    const float* emb = (const float*)d_in[1];
    const float* Wq  = (const float*)d_in[2];
    const float* bq  = (const float*)d_in[3];
    const float* Wk  = (const float*)d_in[4];
    const float* bk  = (const float*)d_in[5];
    const float* Wv  = (const float*)d_in[6];
    const float* bv  = (const float*)d_in[7];
    const float* Wo  = (const float*)d_in[8];
    const float* bo  = (const float*)d_in[9];
    const float* g1  = (const float*)d_in[10];
    const float* be1 = (const float*)d_in[11];
    const float* W1  = (const float*)d_in[12];
    const float* b1  = (const float*)d_in[13];
    const float* W2  = (const float*)d_in[14];
    const float* b2  = (const float*)d_in[15];
    const float* g2  = (const float*)d_in[16];
    const float* be2 = (const float*)d_in[17];
    const float* Wc  = (const float*)d_in[18];
    const float* bc  = (const float*)d_in[19];
    float* outp = (float*)d_out;

    float* ws = (float*)d_ws;
    const size_t TD = (size_t)NTOK * D_MODEL;
    float* x  = ws;
    float* qb = ws + TD;
    float* kb = ws + 2*TD;
    float* vb = ws + 3*TD;
    float* t0 = ws + 4*TD;
    float* t1 = ws + 5*TD;
    float* hh = qb;          // FFN hidden aliases q/k/v/t0 region (dead there)

    embed_kernel<<<NTOK, 256, 0, stream>>>(ids, emb, x);

    dim3 gProj(NTOK/64, D_MODEL/64);
    dim3 gFF1 (NTOK/64, FFDIM/64);
    dim3 gAttn(SS/64, NHEADS, BB);

    for (int l = 0; l < NLAYERS; ++l) {
        const float* Wq_l = Wq + (size_t)l * D_MODEL * D_MODEL;
        const float* Wk_l = Wk + (size_t)l * D_MODEL * D_MODEL;
        const float* Wv_l = Wv + (size_t)l * D_MODEL * D_MODEL;
        const float* Wo_l = Wo + (size_t)l * D_MODEL * D_MODEL;
        const float* W1_l = W1 + (size_t)l * D_MODEL * FFDIM;
        const float* W2_l = W2 + (size_t)l * FFDIM * D_MODEL;

        gemm_kernel<0><<<gProj, 256, 0, stream>>>(x, Wq_l, bq + l*D_MODEL, qb, NTOK, D_MODEL, D_MODEL);
        gemm_kernel<0><<<gProj, 256, 0, stream>>>(x, Wk_l, bk + l*D_MODEL, kb, NTOK, D_MODEL, D_MODEL);
        gemm_kernel<0><<<gProj, 256, 0, stream>>>(x, Wv_l, bv + l*D_MODEL, vb, NTOK, D_MODEL, D_MODEL);
        flash_mfma_kernel<<<gAttn, 256, 0, stream>>>(qb, kb, vb, ids, t0);
        gemm_kernel<0><<<gProj, 256, 0, stream>>>(t0, Wo_l, bo + l*D_MODEL, t1, NTOK, D_MODEL, D_MODEL);
        ln_kernel<<<NTOK/4, 256, 0, stream>>>(x, t1, g1 + l*D_MODEL, be1 + l*D_MODEL, x);

        gemm_kernel<1><<<gFF1, 256, 0, stream>>>(x, W1_l, b1 + l*FFDIM, hh, NTOK, D_MODEL, FFDIM);
        gemm_kernel<0><<<gProj, 256, 0, stream>>>(hh, W2_l, b2 + l*D_MODEL, t1, NTOK, FFDIM, D_MODEL);
        ln_kernel<<<NTOK/4, 256, 0, stream>>>(x, t1, g2 + l*D_MODEL, be2 + l*D_MODEL, x);
    }

    pool1_kernel<<<BB*16, 256, 0, stream>>>(x, ids, t1);
    pool2_kernel<<<BB, 256, 0, stream>>>(t1, ids, t0);
    cls_kernel<<<1, 256, 0, stream>>>(t0, Wc, bc, outp);
}

// Round 3
// 1705.617 us; speedup vs baseline: 7.2010x; 3.3615x over previous
//
#include <hip/hip_runtime.h>
#include <math.h>

#define D_MODEL 256
#define NHEADS 4
#define DK 64
#define NLAYERS 4
#define FFDIM 1024
#define BB 16
#define SS 2048
#define NTOK (BB*SS)

typedef __attribute__((ext_vector_type(8))) short bf16x8;
typedef __attribute__((ext_vector_type(4))) short s16x4;
typedef __attribute__((ext_vector_type(4))) float f32x4;

__device__ __forceinline__ short f2bf(float f) {
    unsigned u = __float_as_uint(f);
    unsigned r = (u + 0x7fffu + ((u >> 16) & 1u)) >> 16;
    return (short)r;
}

// ---------------------------------------------------------------- embedding + posenc (dual write)
__global__ void embed_kernel(const int* __restrict__ ids, const float* __restrict__ emb,
                             float* __restrict__ x, short* __restrict__ xb) {
    int idx = blockIdx.x * 256 + threadIdx.x;
    int tok = idx >> 8;
    int d   = idx & 255;
    int s   = tok & (SS - 1);
    int id  = ids[tok];
    float e = emb[id * D_MODEL + d] * 16.0f;
    float i2 = (float)((d >> 1) << 1);
    float div = expf(i2 * (-9.210340371976184f / 256.0f));
    float ang = (float)s * div;
    float pe = (d & 1) ? cosf(ang) : sinf(ang);
    float val = e + pe;
    x[idx] = val;
    xb[idx] = f2bf(val);
}

// ---------------------------------------------------------------- weight prep: transpose + bf16
// grid (64, 6, NLAYERS), block 256. dst[m][k] = bf16(src[k][m]) per layer.
__global__ void wprep_kernel(const float* __restrict__ Wq, const float* __restrict__ Wk,
                             const float* __restrict__ Wv, const float* __restrict__ Wo,
                             const float* __restrict__ W1, const float* __restrict__ W2,
                             short* __restrict__ wtq, short* __restrict__ wtk,
                             short* __restrict__ wtv, short* __restrict__ wto,
                             short* __restrict__ w1t, short* __restrict__ w2t) {
    int wid = blockIdx.y, l = blockIdx.z, tile = blockIdx.x;
    int K = (wid == 5) ? 1024 : 256;
    int M = (wid == 4) ? 1024 : 256;
    int tiles = (K >> 6) * (M >> 6);
    if (tile >= tiles) return;
    const float* src; short* dst;
    switch (wid) {
        case 0: src = Wq; dst = wtq; break;
        case 1: src = Wk; dst = wtk; break;
        case 2: src = Wv; dst = wtv; break;
        case 3: src = Wo; dst = wto; break;
        case 4: src = W1; dst = w1t; break;
        default: src = W2; dst = w2t; break;
    }
    src += (size_t)l * K * M;
    dst += (size_t)l * K * M;
    int tm = tile % (M >> 6), tk = tile / (M >> 6);

    __shared__ short t_s[64][68];
    int tid = threadIdx.x;
    #pragma unroll
    for (int u = 0; u < 16; ++u) {
        int e = tid + u * 256;
        int r = e >> 6, c = e & 63;          // r = k-local, c = m-local
        t_s[c][r] = f2bf(src[(size_t)(tk*64 + r) * M + tm*64 + c]);
    }
    __syncthreads();
    #pragma unroll
    for (int u = 0; u < 4; ++u) {
        int e = tid + u * 256;
        int r = e >> 4, c4 = (e & 15) * 4;   // r = m-local
        s16x4 v;
        v[0] = t_s[r][c4]; v[1] = t_s[r][c4+1]; v[2] = t_s[r][c4+2]; v[3] = t_s[r][c4+3];
        *(s16x4*)&dst[(size_t)(tm*64 + r) * K + tk*64 + c4] = v;
    }
}

// ---------------------------------------------------------------- bf16 MFMA GEMM
// C[N][M] = A[N][K] @ Wt[M][K]^T + bias. 128x128 tile, BK=64, 4 waves (2x2), 64x64/wave.
template<int RELU, int OUT_BF16>
__global__ __launch_bounds__(256) void gemm_bf16_kernel(
        const short* __restrict__ A, const short* __restrict__ Wt,
        const float* __restrict__ bias, void* __restrict__ Cout,
        int N, int K, int M) {
    __shared__ short A_s[128][72];
    __shared__ short B_s[128][72];
    int tid = threadIdx.x;
    int w = tid >> 6, lane = tid & 63;
    int lr = lane & 15, lg = lane >> 4;
    int wr = w >> 1, wc = w & 1;
    int rowBase = blockIdx.x * 128;
    int colBase = blockIdx.y * 128;

    f32x4 acc[4][4];
    #pragma unroll
    for (int m = 0; m < 4; ++m)
        #pragma unroll
        for (int n = 0; n < 4; ++n)
            acc[m][n] = (f32x4){0.f, 0.f, 0.f, 0.f};

    for (int kt = 0; kt < K; kt += 64) {
        #pragma unroll
        for (int u = 0; u < 4; ++u) {
            int e = tid + u * 256;
            int r = e >> 3, c8 = (e & 7) * 8;
            *(bf16x8*)&A_s[r][c8] = *(const bf16x8*)(A + (size_t)(rowBase + r) * K + kt + c8);
        }
        #pragma unroll
        for (int u = 0; u < 4; ++u) {
            int e = tid + u * 256;
            int r = e >> 3, c8 = (e & 7) * 8;
            *(bf16x8*)&B_s[r][c8] = *(const bf16x8*)(Wt + (size_t)(colBase + r) * K + kt + c8);
        }
        __syncthreads();
        #pragma unroll
        for (int ks = 0; ks < 2; ++ks) {
            bf16x8 af[4], bfr[4];
            #pragma unroll
            for (int m = 0; m < 4; ++m)
                af[m] = *(const bf16x8*)&A_s[wr*64 + m*16 + lr][ks*32 + lg*8];
            #pragma unroll
            for (int n = 0; n < 4; ++n)
                bfr[n] = *(const bf16x8*)&B_s[wc*64 + n*16 + lr][ks*32 + lg*8];
            #pragma unroll
            for (int m = 0; m < 4; ++m)
                #pragma unroll
                for (int n = 0; n < 4; ++n)
                    acc[m][n] = __builtin_amdgcn_mfma_f32_16x16x32_bf16(af[m], bfr[n], acc[m][n], 0, 0, 0);
        }
        __syncthreads();
    }

    #pragma unroll
    for (int m = 0; m < 4; ++m) {
        int row = rowBase + wr*64 + m*16 + lg*4;
        #pragma unroll
        for (int n = 0; n < 4; ++n) {
            int col = colBase + wc*64 + n*16 + lr;
            float bv = bias[col];
            #pragma unroll
            for (int r = 0; r < 4; ++r) {
                float vv = acc[m][n][r] + bv;
                if (RELU) vv = fmaxf(vv, 0.0f);
                if (OUT_BF16) ((short*)Cout)[(size_t)(row + r) * M + col] = f2bf(vv);
                else          ((float*)Cout)[(size_t)(row + r) * M + col] = vv;
            }
        }
    }
}

// ---------------------------------------------------------------- bf16 MFMA flash attention
// grid: (SS/64, NHEADS, BB); block 256 = 4 waves. V stored XOR-swizzled transposed.
__global__ __launch_bounds__(256) void flash_mfma_kernel(
        const short* __restrict__ q, const short* __restrict__ k,
        const short* __restrict__ v, const int* __restrict__ ids,
        short* __restrict__ out) {
    __shared__ short k_s[64][72];        // [key][d]
    __shared__ short vt_s[64][72];       // [d][swz(key)]
    __shared__ short p_s[4][16][72];     // per-wave P [q][key]
    __shared__ float madd_s[64];

    int qb = blockIdx.x, h = blockIdx.y, b = blockIdx.z;
    int tid = threadIdx.x;
    int w = tid >> 6, lane = tid & 63;
    int lr = lane & 15, lg = lane >> 4;

    const short* qp = q + (size_t)b * SS * D_MODEL + h * DK;
    const short* kp = k + (size_t)b * SS * D_MODEL + h * DK;
    const short* vp = v + (size_t)b * SS * D_MODEL + h * DK;

    int qrow = qb*64 + w*16 + lr;
    bf16x8 qf[2];
    #pragma unroll
    for (int ks = 0; ks < 2; ++ks)
        qf[ks] = *(const bf16x8*)(qp + (size_t)qrow * D_MODEL + lg*8 + ks*32);

    f32x4 o[4];
    float m_i[4], l_i[4];
    #pragma unroll
    for (int r = 0; r < 4; ++r) {
        m_i[r] = -1e30f; l_i[r] = 0.0f;
        o[r] = (f32x4){0.f, 0.f, 0.f, 0.f};
    }

    for (int kb = 0; kb < SS/64; ++kb) {
        __syncthreads();
        // K: 64x64 bf16, row-major; V: transposed + XOR-swizzled
        #pragma unroll
        for (int u = 0; u < 2; ++u) {
            int e = tid + u * 256;
            int r = e >> 3, c8 = (e & 7) * 8;
            *(bf16x8*)&k_s[r][c8] = *(const bf16x8*)(kp + (size_t)(kb*64 + r) * D_MODEL + c8);
            bf16x8 vv = *(const bf16x8*)(vp + (size_t)(kb*64 + r) * D_MODEL + c8);
            #pragma unroll
            for (int j = 0; j < 8; ++j) {
                int col = c8 + j;
                vt_s[col][((((r >> 3) ^ (col >> 3)) << 3) | (r & 7))] = vv[j];
            }
        }
        if (tid < 64)
            madd_s[tid] = (ids[b*SS + kb*64 + tid] != 0) ? 0.0f : -1e30f;
        __syncthreads();

        float mk[4];
        #pragma unroll
        for (int t = 0; t < 4; ++t) mk[t] = madd_s[lr + 16*t];

        f32x4 s[4];
        #pragma unroll
        for (int t = 0; t < 4; ++t) {
            bf16x8 kf0 = *(const bf16x8*)&k_s[t*16 + lr][lg*8];
            bf16x8 kf1 = *(const bf16x8*)&k_s[t*16 + lr][lg*8 + 32];
            f32x4 acc = (f32x4){0.f, 0.f, 0.f, 0.f};
            acc = __builtin_amdgcn_mfma_f32_16x16x32_bf16(qf[0], kf0, acc, 0, 0, 0);
            acc = __builtin_amdgcn_mfma_f32_16x16x32_bf16(qf[1], kf1, acc, 0, 0, 0);
            s[t] = acc;
        }

        #pragma unroll
        for (int r = 0; r < 4; ++r) {
            float sr[4];
            #pragma unroll
            for (int t = 0; t < 4; ++t) sr[t] = s[t][r] * 0.125f + mk[t];
            float mx = fmaxf(fmaxf(sr[0], sr[1]), fmaxf(sr[2], sr[3]));
            #pragma unroll
            for (int off = 1; off < 16; off <<= 1)
                mx = fmaxf(mx, __shfl_xor(mx, off));
            float mnew = fmaxf(m_i[r], mx);
            float alpha = __expf(m_i[r] - mnew);
            float p[4], rsum = 0.0f;
            #pragma unroll
            for (int t = 0; t < 4; ++t) {
                p[t] = (sr[t] < -5e29f) ? 0.0f : __expf(sr[t] - mnew);
                rsum += p[t];
            }
            #pragma unroll
            for (int off = 1; off < 16; off <<= 1)
                rsum += __shfl_xor(rsum, off);
            l_i[r] = l_i[r] * alpha + rsum;
            m_i[r] = mnew;
            #pragma unroll
            for (int dt = 0; dt < 4; ++dt) o[dt][r] *= alpha;
            #pragma unroll
            for (int t = 0; t < 4; ++t)
                p_s[w][lg*4 + r][lr + 16*t] = f2bf(p[t]);
        }
        // per-wave p_s: no barrier needed

        bf16x8 pa[2];
        #pragma unroll
        for (int ks = 0; ks < 2; ++ks)
            pa[ks] = *(const bf16x8*)&p_s[w][lr][ks*32 + lg*8];
        #pragma unroll
        for (int dt = 0; dt < 4; ++dt) {
            int col = dt*16 + lr;
            #pragma unroll
            for (int ks = 0; ks < 2; ++ks) {
                bf16x8 vb = *(const bf16x8*)&vt_s[col][(((ks*4 + lg) ^ (col >> 3)) << 3)];
                o[dt] = __builtin_amdgcn_mfma_f32_16x16x32_bf16(pa[ks], vb, o[dt], 0, 0, 0);
            }
        }
    }

    #pragma unroll
    for (int r = 0; r < 4; ++r) {
        float inv = 1.0f / l_i[r];
        int row = b*SS + qb*64 + w*16 + lg*4 + r;
        #pragma unroll
        for (int dt = 0; dt < 4; ++dt)
            out[(size_t)row * D_MODEL + h*DK + dt*16 + lr] = f2bf(o[dt][r] * inv);
    }
}

// ---------------------------------------------------------------- fused residual + LN (dual write)
__global__ void ln_kernel(const float* __restrict__ resid, const float* __restrict__ y,
                          const float* __restrict__ g, const float* __restrict__ be,
                          float* __restrict__ outf, short* __restrict__ outb) {
    int wave = threadIdx.x >> 6;
    int lane = threadIdx.x & 63;
    int row = blockIdx.x * 4 + wave;
    size_t base = (size_t)row * D_MODEL + lane * 4;

    float4 a = *(const float4*)(resid + base);
    float4 bv = *(const float4*)(y + base);
    float v0 = a.x + bv.x, v1 = a.y + bv.y, v2 = a.z + bv.z, v3 = a.w + bv.w;

    float sum = v0 + v1 + v2 + v3;
    #pragma unroll
    for (int off = 1; off < 64; off <<= 1) sum += __shfl_xor(sum, off);
    float mu = sum * (1.0f / 256.0f);

    float d0 = v0 - mu, d1 = v1 - mu, d2 = v2 - mu, d3 = v3 - mu;
    float vs = d0*d0 + d1*d1 + d2*d2 + d3*d3;
    #pragma unroll
    for (int off = 1; off < 64; off <<= 1) vs += __shfl_xor(vs, off);
    float rstd = rsqrtf(vs * (1.0f / 256.0f) + 1e-5f);

    int c = lane * 4;
    float4 gv = *(const float4*)(g + c);
    float4 bev = *(const float4*)(be + c);
    float4 o;
    o.x = d0 * rstd * gv.x + bev.x;
    o.y = d1 * rstd * gv.y + bev.y;
    o.z = d2 * rstd * gv.z + bev.z;
    o.w = d3 * rstd * gv.w + bev.w;
    *(float4*)(outf + base) = o;
    s16x4 ob; ob[0] = f2bf(o.x); ob[1] = f2bf(o.y); ob[2] = f2bf(o.z); ob[3] = f2bf(o.w);
    *(s16x4*)(outb + base) = ob;
}

// ---------------------------------------------------------------- masked mean pool (2-stage)
__global__ void pool1_kernel(const float* __restrict__ x, const int* __restrict__ ids,
                             float* __restrict__ partial) {
    int b = blockIdx.x >> 4, chunk = blockIdx.x & 15;
    int d = threadIdx.x;
    float acc = 0.0f;
    int s0 = chunk * 128;
    for (int s = s0; s < s0 + 128; ++s) {
        if (ids[b*SS + s] != 0) acc += x[(size_t)(b*SS + s) * D_MODEL + d];
    }
    partial[(size_t)(b*16 + chunk) * D_MODEL + d] = acc;
}

__global__ void pool2_kernel(const float* __restrict__ partial, const int* __restrict__ ids,
                             float* __restrict__ pooled) {
    int b = blockIdx.x;
    int d = threadIdx.x;
    float acc = 0.0f;
    for (int c = 0; c < 16; ++c) acc += partial[(size_t)(b*16 + c) * D_MODEL + d];
    int cnt = 0;
    for (int s = threadIdx.x; s < SS; s += 256) cnt += (ids[b*SS + s] != 0);
    __shared__ int cs[256];
    cs[threadIdx.x] = cnt;
    __syncthreads();
    for (int off = 128; off > 0; off >>= 1) {
        if (threadIdx.x < off) cs[threadIdx.x] += cs[threadIdx.x + off];
        __syncthreads();
    }
    float total = (float)cs[0];
    pooled[b * D_MODEL + d] = acc / fmaxf(total, 1e-9f);
}

// ---------------------------------------------------------------- classifier 16x10
__global__ void cls_kernel(const float* __restrict__ pooled, const float* __restrict__ Wc,
                           const float* __restrict__ bc, float* __restrict__ outp) {
    int t = threadIdx.x;
    if (t >= BB * 10) return;
    int b = t / 10, c = t % 10;
    float acc = bc[c];
    for (int d = 0; d < D_MODEL; ++d)
        acc += pooled[b * D_MODEL + d] * Wc[d * 10 + c];
    outp[t] = acc;
}

// ---------------------------------------------------------------- launch
extern "C" void kernel_launch(void* const* d_in, const int* in_sizes, int n_in,
                              void* d_out, int out_size, void* d_ws, size_t ws_size,
                              hipStream_t stream) {
    const int*   ids = (const int*)  d_in[0];
    const float* emb = (const float*)d_in[1];
    const float* Wq  = (const float*)d_in[2];
    const float* bq  = (const float*)d_in[3];
    const float* Wk  = (const float*)d_in[4];
    const float* bk  = (const float*)d_in[5];
    const float* Wv  = (const float*)d_in[6];
    const float* bv  = (const float*)d_in[7];
    const float* Wo  = (const float*)d_in[8];
    const float* bo  = (const float*)d_in[9];
    const float* g1  = (const float*)d_in[10];
    const float* be1 = (const float*)d_in[11];
    const float* W1  = (const float*)d_in[12];
    const float* b1  = (const float*)d_in[13];
    const float* W2  = (const float*)d_in[14];
    const float* b2  = (const float*)d_in[15];
    const float* g2  = (const float*)d_in[16];
    const float* be2 = (const float*)d_in[17];
    const float* Wc  = (const float*)d_in[18];
    const float* bc  = (const float*)d_in[19];
    float* outp = (float*)d_out;

    const size_t TD = (size_t)NTOK * D_MODEL;     // 8.39M elems
    float* ws   = (float*)d_ws;
    float* x    = ws;                              // residual fp32
    float* t1   = ws + TD;                         // fp32 GEMM out (O-proj / FF2)
    short* sb   = (short*)(ws + 2*TD);
    short* xb   = sb;                              // x bf16
    short* qb   = sb + TD;
    short* kb   = sb + 2*TD;
    short* vb   = sb + 3*TD;
    short* t0   = sb + 4*TD;                       // attn out bf16
    short* hh   = sb + TD;                         // FFN hidden (aliases qb..t0, dead)
    const size_t WSZP = 65536, WSZF = 262144;
    short* wtq  = sb + 5*TD;
    short* wtk  = wtq + NLAYERS*WSZP;
    short* wtv  = wtk + NLAYERS*WSZP;
    short* wto  = wtv + NLAYERS*WSZP;
    short* w1t  = wto + NLAYERS*WSZP;
    short* w2t  = w1t + NLAYERS*WSZF;
    float* poolp = t1;                             // pool scratch (t1 dead after loop)
    float* pooled = t1 + 65536;

    wprep_kernel<<<dim3(64, 6, NLAYERS), 256, 0, stream>>>(Wq, Wk, Wv, Wo, W1, W2,
                                                           wtq, wtk, wtv, wto, w1t, w2t);
    embed_kernel<<<NTOK, 256, 0, stream>>>(ids, emb, x, xb);

    dim3 gP(NTOK/128, D_MODEL/128);    // (256, 2)
    dim3 gF1(NTOK/128, FFDIM/128);     // (256, 8)
    dim3 gAttn(SS/64, NHEADS, BB);

    for (int l = 0; l < NLAYERS; ++l) {
        gemm_bf16_kernel<0,1><<<gP, 256, 0, stream>>>(xb, wtq + l*WSZP, bq + l*D_MODEL, qb, NTOK, D_MODEL, D_MODEL);
        gemm_bf16_kernel<0,1><<<gP, 256, 0, stream>>>(xb, wtk + l*WSZP, bk + l*D_MODEL, kb, NTOK, D_MODEL, D_MODEL);
        gemm_bf16_kernel<0,1><<<gP, 256, 0, stream>>>(xb, wtv + l*WSZP, bv + l*D_MODEL, vb, NTOK, D_MODEL, D_MODEL);
        flash_mfma_kernel<<<gAttn, 256, 0, stream>>>(qb, kb, vb, ids, t0);
        gemm_bf16_kernel<0,0><<<gP, 256, 0, stream>>>(t0, wto + l*WSZP, bo + l*D_MODEL, t1, NTOK, D_MODEL, D_MODEL);
        ln_kernel<<<NTOK/4, 256, 0, stream>>>(x, t1, g1 + l*D_MODEL, be1 + l*D_MODEL, x, xb);

        gemm_bf16_kernel<1,1><<<gF1, 256, 0, stream>>>(xb, w1t + l*WSZF, b1 + l*FFDIM, hh, NTOK, D_MODEL, FFDIM);
        gemm_bf16_kernel<0,0><<<gP, 256, 0, stream>>>(hh, w2t + l*WSZF, b2 + l*D_MODEL, t1, NTOK, FFDIM, D_MODEL);
        ln_kernel<<<NTOK/4, 256, 0, stream>>>(x, t1, g2 + l*D_MODEL, be2 + l*D_MODEL, x, xb);
    }

    pool1_kernel<<<BB*16, 256, 0, stream>>>(x, ids, poolp);
    pool2_kernel<<<BB, 256, 0, stream>>>(poolp, ids, pooled);
    cls_kernel<<<1, 256, 0, stream>>>(pooled, Wc, bc, outp);
}

// Round 4
// 1497.708 us; speedup vs baseline: 8.2006x; 1.1388x over previous
//
#include <hip/hip_runtime.h>
#include <math.h>

#define D_MODEL 256
#define NHEADS 4
#define DK 64
#define NLAYERS 4
#define FFDIM 1024
#define BB 16
#define SS 2048
#define NTOK (BB*SS)

typedef __attribute__((ext_vector_type(8))) short bf16x8;
typedef __attribute__((ext_vector_type(4))) short s16x4;
typedef __attribute__((ext_vector_type(4))) float f32x4;

__device__ __forceinline__ short f2bf(float f) {
    unsigned u = __float_as_uint(f);
    unsigned r = (u + 0x7fffu + ((u >> 16) & 1u)) >> 16;
    return (short)r;
}

// ---------------------------------------------------------------- embedding + posenc (dual write)
__global__ void embed_kernel(const int* __restrict__ ids, const float* __restrict__ emb,
                             float* __restrict__ x, short* __restrict__ xb) {
    int idx = blockIdx.x * 256 + threadIdx.x;
    int tok = idx >> 8;
    int d   = idx & 255;
    int s   = tok & (SS - 1);
    int id  = ids[tok];
    float e = emb[id * D_MODEL + d] * 16.0f;
    float i2 = (float)((d >> 1) << 1);
    float div = expf(i2 * (-9.210340371976184f / 256.0f));
    float ang = (float)s * div;
    float pe = (d & 1) ? cosf(ang) : sinf(ang);
    float val = e + pe;
    x[idx] = val;
    xb[idx] = f2bf(val);
}

// ---------------------------------------------------------------- weight prep: transpose + bf16
// wid 0,1,2 -> fused wqkv[l][768][256]; 3 -> wto; 4 -> w1t; 5 -> w2t
__global__ void wprep_kernel(const float* __restrict__ Wq, const float* __restrict__ Wk,
                             const float* __restrict__ Wv, const float* __restrict__ Wo,
                             const float* __restrict__ W1, const float* __restrict__ W2,
                             short* __restrict__ wqkv, short* __restrict__ wto,
                             short* __restrict__ w1t, short* __restrict__ w2t) {
    int wid = blockIdx.y, l = blockIdx.z, tile = blockIdx.x;
    int K = (wid == 5) ? 1024 : 256;
    int M = (wid == 4) ? 1024 : 256;
    int tiles = (K >> 6) * (M >> 6);
    if (tile >= tiles) return;
    const float* src; short* dst;
    switch (wid) {
        case 0: src = Wq; dst = wqkv + (size_t)l*196608;            break;
        case 1: src = Wk; dst = wqkv + (size_t)l*196608 + 65536;    break;
        case 2: src = Wv; dst = wqkv + (size_t)l*196608 + 131072;   break;
        case 3: src = Wo; dst = wto + (size_t)l*65536;              break;
        case 4: src = W1; dst = w1t + (size_t)l*262144;             break;
        default: src = W2; dst = w2t + (size_t)l*262144;            break;
    }
    src += (size_t)l * K * M;
    int tm = tile % (M >> 6), tk = tile / (M >> 6);

    __shared__ short t_s[64][68];
    int tid = threadIdx.x;
    #pragma unroll
    for (int u = 0; u < 16; ++u) {
        int e = tid + u * 256;
        int r = e >> 6, c = e & 63;
        t_s[c][r] = f2bf(src[(size_t)(tk*64 + r) * M + tm*64 + c]);
    }
    __syncthreads();
    #pragma unroll
    for (int u = 0; u < 4; ++u) {
        int e = tid + u * 256;
        int r = e >> 4, c4 = (e & 15) * 4;
        s16x4 v;
        v[0] = t_s[r][c4]; v[1] = t_s[r][c4+1]; v[2] = t_s[r][c4+2]; v[3] = t_s[r][c4+3];
        *(s16x4*)&dst[(size_t)(tm*64 + r) * K + tk*64 + c4] = v;
    }
}

// ---------------------------------------------------------------- fused QKV bias concat
__global__ void bprep_kernel(const float* __restrict__ bq, const float* __restrict__ bk,
                             const float* __restrict__ bv, float* __restrict__ bqkv) {
    int idx = blockIdx.x * 256 + threadIdx.x;
    if (idx >= NLAYERS * 768) return;
    int l = idx / 768, j = idx % 768;
    float v;
    if (j < 256) v = bq[l*256 + j];
    else if (j < 512) v = bk[l*256 + j - 256];
    else v = bv[l*256 + j - 512];
    bqkv[idx] = v;
}

// ---------------------------------------------------------------- bf16 MFMA GEMM (generic)
// C[N][M] = A[N][K] @ Wt[M][K]^T + bias. 128x128 tile, BK=64, 4 waves (2x2).
template<int RELU>
__global__ __launch_bounds__(256) void gemm_bf16_kernel(
        const short* __restrict__ A, const short* __restrict__ Wt,
        const float* __restrict__ bias, short* __restrict__ Cout,
        int N, int K, int M) {
    __shared__ short A_s[128][72];
    __shared__ short B_s[128][72];
    int tid = threadIdx.x;
    int w = tid >> 6, lane = tid & 63;
    int lr = lane & 15, lg = lane >> 4;
    int wr = w >> 1, wc = w & 1;
    int rowBase = blockIdx.x * 128;
    int colBase = blockIdx.y * 128;

    f32x4 acc[4][4];
    #pragma unroll
    for (int m = 0; m < 4; ++m)
        #pragma unroll
        for (int n = 0; n < 4; ++n)
            acc[m][n] = (f32x4){0.f, 0.f, 0.f, 0.f};

    for (int kt = 0; kt < K; kt += 64) {
        #pragma unroll
        for (int u = 0; u < 4; ++u) {
            int e = tid + u * 256;
            int r = e >> 3, c8 = (e & 7) * 8;
            *(bf16x8*)&A_s[r][c8] = *(const bf16x8*)(A + (size_t)(rowBase + r) * K + kt + c8);
        }
        #pragma unroll
        for (int u = 0; u < 4; ++u) {
            int e = tid + u * 256;
            int r = e >> 3, c8 = (e & 7) * 8;
            *(bf16x8*)&B_s[r][c8] = *(const bf16x8*)(Wt + (size_t)(colBase + r) * K + kt + c8);
        }
        __syncthreads();
        #pragma unroll
        for (int ks = 0; ks < 2; ++ks) {
            bf16x8 af[4], bfr[4];
            #pragma unroll
            for (int m = 0; m < 4; ++m)
                af[m] = *(const bf16x8*)&A_s[wr*64 + m*16 + lr][ks*32 + lg*8];
            #pragma unroll
            for (int n = 0; n < 4; ++n)
                bfr[n] = *(const bf16x8*)&B_s[wc*64 + n*16 + lr][ks*32 + lg*8];
            #pragma unroll
            for (int m = 0; m < 4; ++m)
                #pragma unroll
                for (int n = 0; n < 4; ++n)
                    acc[m][n] = __builtin_amdgcn_mfma_f32_16x16x32_bf16(af[m], bfr[n], acc[m][n], 0, 0, 0);
        }
        __syncthreads();
    }

    #pragma unroll
    for (int m = 0; m < 4; ++m) {
        int row = rowBase + wr*64 + m*16 + lg*4;
        #pragma unroll
        for (int n = 0; n < 4; ++n) {
            int col = colBase + wc*64 + n*16 + lr;
            float bv = bias[col];
            #pragma unroll
            for (int r = 0; r < 4; ++r) {
                float vv = acc[m][n][r] + bv;
                if (RELU) vv = fmaxf(vv, 0.0f);
                Cout[(size_t)(row + r) * M + col] = f2bf(vv);
            }
        }
    }
}

// ---------------------------------------------------------------- bf16 GEMM + residual + LN fused
// x_new = LN(resid + A@Wt^T + bias)*g + be; writes xf fp32 + xb bf16. M=256 fixed.
// Tile: 64 rows x 256 cols (full row). 4 waves, wave w = col group w*64.
__global__ __launch_bounds__(256) void gemm_ln_kernel(
        const short* __restrict__ A, const short* __restrict__ Wt,
        const float* __restrict__ bias, const float* __restrict__ resid,
        const float* __restrict__ g, const float* __restrict__ be,
        float* __restrict__ xf, short* __restrict__ xb, int K) {
    __shared__ short A_s[64][72];
    __shared__ short B_s[256][72];
    __shared__ float red_s[2][4][64];
    __shared__ float mu_s[64], rs_s[64];
    int tid = threadIdx.x;
    int w = tid >> 6, lane = tid & 63;
    int lr = lane & 15, lg = lane >> 4;
    int rowBase = blockIdx.x * 64;
    int colW = w * 64;

    f32x4 acc[4][4];
    #pragma unroll
    for (int m = 0; m < 4; ++m)
        #pragma unroll
        for (int n = 0; n < 4; ++n)
            acc[m][n] = (f32x4){0.f, 0.f, 0.f, 0.f};

    for (int kt = 0; kt < K; kt += 64) {
        #pragma unroll
        for (int u = 0; u < 2; ++u) {
            int e = tid + u * 256;
            int r = e >> 3, c8 = (e & 7) * 8;
            *(bf16x8*)&A_s[r][c8] = *(const bf16x8*)(A + (size_t)(rowBase + r) * K + kt + c8);
        }
        #pragma unroll
        for (int u = 0; u < 8; ++u) {
            int e = tid + u * 256;
            int r = e >> 3, c8 = (e & 7) * 8;
            *(bf16x8*)&B_s[r][c8] = *(const bf16x8*)(Wt + (size_t)r * K + kt + c8);
        }
        __syncthreads();
        #pragma unroll
        for (int ks = 0; ks < 2; ++ks) {
            bf16x8 af[4], bfr[4];
            #pragma unroll
            for (int m = 0; m < 4; ++m)
                af[m] = *(const bf16x8*)&A_s[m*16 + lr][ks*32 + lg*8];
            #pragma unroll
            for (int n = 0; n < 4; ++n)
                bfr[n] = *(const bf16x8*)&B_s[colW + n*16 + lr][ks*32 + lg*8];
            #pragma unroll
            for (int m = 0; m < 4; ++m)
                #pragma unroll
                for (int n = 0; n < 4; ++n)
                    acc[m][n] = __builtin_amdgcn_mfma_f32_16x16x32_bf16(af[m], bfr[n], acc[m][n], 0, 0, 0);
        }
        __syncthreads();
    }

    // epilogue: add bias + residual, row-LN over 256 cols
    #pragma unroll
    for (int m = 0; m < 4; ++m) {
        #pragma unroll
        for (int n = 0; n < 4; ++n) {
            int col = colW + n*16 + lr;
            float bv = bias[col];
            #pragma unroll
            for (int r = 0; r < 4; ++r) {
                int row = rowBase + m*16 + lg*4 + r;
                acc[m][n][r] += bv + resid[(size_t)row * 256 + col];
            }
        }
    }
    #pragma unroll
    for (int m = 0; m < 4; ++m) {
        #pragma unroll
        for (int r = 0; r < 4; ++r) {
            float sum = acc[m][0][r] + acc[m][1][r] + acc[m][2][r] + acc[m][3][r];
            float sq  = acc[m][0][r]*acc[m][0][r] + acc[m][1][r]*acc[m][1][r]
                      + acc[m][2][r]*acc[m][2][r] + acc[m][3][r]*acc[m][3][r];
            #pragma unroll
            for (int off = 1; off < 16; off <<= 1) {
                sum += __shfl_xor(sum, off);
                sq  += __shfl_xor(sq, off);
            }
            if (lr == 0) {
                red_s[0][w][m*16 + lg*4 + r] = sum;
                red_s[1][w][m*16 + lg*4 + r] = sq;
            }
        }
    }
    __syncthreads();
    if (tid < 64) {
        float s = red_s[0][0][tid] + red_s[0][1][tid] + red_s[0][2][tid] + red_s[0][3][tid];
        float q = red_s[1][0][tid] + red_s[1][1][tid] + red_s[1][2][tid] + red_s[1][3][tid];
        float mu = s * (1.0f/256.0f);
        float var = q * (1.0f/256.0f) - mu*mu;
        mu_s[tid] = mu;
        rs_s[tid] = rsqrtf(var + 1e-5f);
    }
    __syncthreads();
    #pragma unroll
    for (int m = 0; m < 4; ++m) {
        #pragma unroll
        for (int n = 0; n < 4; ++n) {
            int col = colW + n*16 + lr;
            float gv = g[col], bev = be[col];
            #pragma unroll
            for (int r = 0; r < 4; ++r) {
                int rloc = m*16 + lg*4 + r;
                int row = rowBase + rloc;
                float o = (acc[m][n][r] - mu_s[rloc]) * rs_s[rloc] * gv + bev;
                xf[(size_t)row * 256 + col] = o;
                xb[(size_t)row * 256 + col] = f2bf(o);
            }
        }
    }
}

// ---------------------------------------------------------------- bf16 MFMA flash attention
// grid: (SS/128, NHEADS, BB); block 256 = 4 waves; each wave 32 q-rows (2 sets of 16).
// q/k/v from fused qkv [tok][768]: q at +0, k at +256, v at +512 (per-head +h*64).
__global__ __launch_bounds__(256) void flash_mfma_kernel(
        const short* __restrict__ qkv, const int* __restrict__ ids,
        short* __restrict__ out) {
    __shared__ short k_s[64][72];        // [key][d]
    __shared__ short vt_s[64][72];       // [d][swz(key)]
    __shared__ short p_s[4][32][72];     // per-wave P [q(2 sets)][key]
    __shared__ float madd_s[64];

    int qb = blockIdx.x, h = blockIdx.y, b = blockIdx.z;
    int tid = threadIdx.x;
    int w = tid >> 6, lane = tid & 63;
    int lr = lane & 15, lg = lane >> 4;

    const short* qp = qkv + (size_t)b * SS * 768 + h * DK;
    const short* kp = qp + 256;
    const short* vp = qp + 512;

    bf16x8 qf[2][2];
    #pragma unroll
    for (int s = 0; s < 2; ++s) {
        int qrow = qb*128 + w*32 + s*16 + lr;
        #pragma unroll
        for (int ks = 0; ks < 2; ++ks)
            qf[s][ks] = *(const bf16x8*)(qp + (size_t)qrow * 768 + lg*8 + ks*32);
    }

    f32x4 o[2][4];
    float m_i[2][4], l_i[2][4];
    #pragma unroll
    for (int s = 0; s < 2; ++s)
        #pragma unroll
        for (int r = 0; r < 4; ++r) {
            m_i[s][r] = -1e30f; l_i[s][r] = 0.0f;
            o[s][r] = (f32x4){0.f, 0.f, 0.f, 0.f};
        }

    for (int kb = 0; kb < SS/64; ++kb) {
        __syncthreads();
        #pragma unroll
        for (int u = 0; u < 2; ++u) {
            int e = tid + u * 256;
            int r = e >> 3, c8 = (e & 7) * 8;
            *(bf16x8*)&k_s[r][c8] = *(const bf16x8*)(kp + (size_t)(kb*64 + r) * 768 + c8);
            bf16x8 vv = *(const bf16x8*)(vp + (size_t)(kb*64 + r) * 768 + c8);
            #pragma unroll
            for (int j = 0; j < 8; ++j) {
                int col = c8 + j;
                vt_s[col][((((r >> 3) ^ (col >> 3)) << 3) | (r & 7))] = vv[j];
            }
        }
        if (tid < 64)
            madd_s[tid] = (ids[b*SS + kb*64 + tid] != 0) ? 0.0f : -1e30f;
        __syncthreads();

        float mk[4];
        #pragma unroll
        for (int t = 0; t < 4; ++t) mk[t] = madd_s[lr + 16*t];

        // S = Q @ K^T for both q-sets; K-frag reads shared
        f32x4 sc[2][4];
        __builtin_amdgcn_s_setprio(1);
        #pragma unroll
        for (int t = 0; t < 4; ++t) {
            bf16x8 kf0 = *(const bf16x8*)&k_s[t*16 + lr][lg*8];
            bf16x8 kf1 = *(const bf16x8*)&k_s[t*16 + lr][lg*8 + 32];
            #pragma unroll
            for (int s = 0; s < 2; ++s) {
                f32x4 a = (f32x4){0.f, 0.f, 0.f, 0.f};
                a = __builtin_amdgcn_mfma_f32_16x16x32_bf16(qf[s][0], kf0, a, 0, 0, 0);
                a = __builtin_amdgcn_mfma_f32_16x16x32_bf16(qf[s][1], kf1, a, 0, 0, 0);
                sc[s][t] = a;
            }
        }
        __builtin_amdgcn_s_setprio(0);

        // online softmax (both sets)
        #pragma unroll
        for (int s = 0; s < 2; ++s) {
            #pragma unroll
            for (int r = 0; r < 4; ++r) {
                float sr[4];
                #pragma unroll
                for (int t = 0; t < 4; ++t) sr[t] = sc[s][t][r] * 0.125f + mk[t];
                float mx = fmaxf(fmaxf(sr[0], sr[1]), fmaxf(sr[2], sr[3]));
                #pragma unroll
                for (int off = 1; off < 16; off <<= 1)
                    mx = fmaxf(mx, __shfl_xor(mx, off));
                float mnew = fmaxf(m_i[s][r], mx);
                float alpha = __expf(m_i[s][r] - mnew);
                float p[4], rsum = 0.0f;
                #pragma unroll
                for (int t = 0; t < 4; ++t) {
                    p[t] = (sr[t] < -5e29f) ? 0.0f : __expf(sr[t] - mnew);
                    rsum += p[t];
                }
                #pragma unroll
                for (int off = 1; off < 16; off <<= 1)
                    rsum += __shfl_xor(rsum, off);
                l_i[s][r] = l_i[s][r] * alpha + rsum;
                m_i[s][r] = mnew;
                #pragma unroll
                for (int dt = 0; dt < 4; ++dt) o[s][dt][r] *= alpha;
                #pragma unroll
                for (int t = 0; t < 4; ++t)
                    p_s[w][s*16 + lg*4 + r][lr + 16*t] = f2bf(p[t]);
            }
        }
        // per-wave p_s: no block barrier needed

        // O += P @ V; V-frag reads shared between sets
        bf16x8 pa[2][2];
        #pragma unroll
        for (int s = 0; s < 2; ++s)
            #pragma unroll
            for (int ks = 0; ks < 2; ++ks)
                pa[s][ks] = *(const bf16x8*)&p_s[w][s*16 + lr][ks*32 + lg*8];
        __builtin_amdgcn_s_setprio(1);
        #pragma unroll
        for (int dt = 0; dt < 4; ++dt) {
            int col = dt*16 + lr;
            #pragma unroll
            for (int ks = 0; ks < 2; ++ks) {
                bf16x8 vb = *(const bf16x8*)&vt_s[col][(((ks*4 + lg) ^ (col >> 3)) << 3)];
                #pragma unroll
                for (int s = 0; s < 2; ++s)
                    o[s][dt] = __builtin_amdgcn_mfma_f32_16x16x32_bf16(pa[s][ks], vb, o[s][dt], 0, 0, 0);
            }
        }
        __builtin_amdgcn_s_setprio(0);
    }

    #pragma unroll
    for (int s = 0; s < 2; ++s)
        #pragma unroll
        for (int r = 0; r < 4; ++r) {
            float inv = 1.0f / l_i[s][r];
            int row = b*SS + qb*128 + w*32 + s*16 + lg*4 + r;
            #pragma unroll
            for (int dt = 0; dt < 4; ++dt)
                out[(size_t)row * 256 + h*DK + dt*16 + lr] = f2bf(o[s][dt][r] * inv);
        }
}

// ---------------------------------------------------------------- masked mean pool (2-stage)
__global__ void pool1_kernel(const float* __restrict__ x, const int* __restrict__ ids,
                             float* __restrict__ partial) {
    int b = blockIdx.x >> 4, chunk = blockIdx.x & 15;
    int d = threadIdx.x;
    float acc = 0.0f;
    int s0 = chunk * 128;
    for (int s = s0; s < s0 + 128; ++s) {
        if (ids[b*SS + s] != 0) acc += x[(size_t)(b*SS + s) * D_MODEL + d];
    }
    partial[(size_t)(b*16 + chunk) * D_MODEL + d] = acc;
}

__global__ void pool2_kernel(const float* __restrict__ partial, const int* __restrict__ ids,
                             float* __restrict__ pooled) {
    int b = blockIdx.x;
    int d = threadIdx.x;
    float acc = 0.0f;
    for (int c = 0; c < 16; ++c) acc += partial[(size_t)(b*16 + c) * D_MODEL + d];
    int cnt = 0;
    for (int s = threadIdx.x; s < SS; s += 256) cnt += (ids[b*SS + s] != 0);
    __shared__ int cs[256];
    cs[threadIdx.x] = cnt;
    __syncthreads();
    for (int off = 128; off > 0; off >>= 1) {
        if (threadIdx.x < off) cs[threadIdx.x] += cs[threadIdx.x + off];
        __syncthreads();
    }
    float total = (float)cs[0];
    pooled[b * D_MODEL + d] = acc / fmaxf(total, 1e-9f);
}

// ---------------------------------------------------------------- classifier 16x10
__global__ void cls_kernel(const float* __restrict__ pooled, const float* __restrict__ Wc,
                           const float* __restrict__ bc, float* __restrict__ outp) {
    int t = threadIdx.x;
    if (t >= BB * 10) return;
    int b = t / 10, c = t % 10;
    float acc = bc[c];
    for (int d = 0; d < D_MODEL; ++d)
        acc += pooled[b * D_MODEL + d] * Wc[d * 10 + c];
    outp[t] = acc;
}

// ---------------------------------------------------------------- launch
extern "C" void kernel_launch(void* const* d_in, const int* in_sizes, int n_in,
                              void* d_out, int out_size, void* d_ws, size_t ws_size,
                              hipStream_t stream) {
    const int*   ids = (const int*)  d_in[0];
    const float* emb = (const float*)d_in[1];
    const float* Wq  = (const float*)d_in[2];
    const float* bq  = (const float*)d_in[3];
    const float* Wk  = (const float*)d_in[4];
    const float* bk  = (const float*)d_in[5];
    const float* Wv  = (const float*)d_in[6];
    const float* bv  = (const float*)d_in[7];
    const float* Wo  = (const float*)d_in[8];
    const float* bo  = (const float*)d_in[9];
    const float* g1  = (const float*)d_in[10];
    const float* be1 = (const float*)d_in[11];
    const float* W1  = (const float*)d_in[12];
    const float* b1  = (const float*)d_in[13];
    const float* W2  = (const float*)d_in[14];
    const float* b2  = (const float*)d_in[15];
    const float* g2  = (const float*)d_in[16];
    const float* be2 = (const float*)d_in[17];
    const float* Wc  = (const float*)d_in[18];
    const float* bc  = (const float*)d_in[19];
    float* outp = (float*)d_out;

    const size_t TD = (size_t)NTOK * D_MODEL;     // 8.39M elems
    float* ws   = (float*)d_ws;
    float* x    = ws;                              // residual fp32
    short* sb   = (short*)(ws + TD);
    short* xb   = sb;                              // TD
    short* qkv  = sb + TD;                         // 3*TD  [tok][768]
    short* t0   = sb + 4*TD;                       // TD (attn out)
    short* hh   = qkv;                             // 4*TD (aliases qkv+t0, dead then)
    short* wqkv = sb + 5*TD;                       // L*768*256
    short* wto  = wqkv + (size_t)NLAYERS*196608;
    short* w1t  = wto  + (size_t)NLAYERS*65536;
    short* w2t  = w1t  + (size_t)NLAYERS*262144;
    float* bqkv = (float*)(w2t + (size_t)NLAYERS*262144);
    float* poolp = bqkv + NLAYERS*768;
    float* pooled = poolp + 65536;

    wprep_kernel<<<dim3(64, 6, NLAYERS), 256, 0, stream>>>(Wq, Wk, Wv, Wo, W1, W2,
                                                           wqkv, wto, w1t, w2t);
    bprep_kernel<<<12, 256, 0, stream>>>(bq, bk, bv, bqkv);
    embed_kernel<<<NTOK, 256, 0, stream>>>(ids, emb, x, xb);

    dim3 gQKV(NTOK/128, 768/128);      // (256, 6)
    dim3 gF1 (NTOK/128, FFDIM/128);    // (256, 8)
    dim3 gAttn(SS/128, NHEADS, BB);    // (16, 4, 16)

    for (int l = 0; l < NLAYERS; ++l) {
        gemm_bf16_kernel<0><<<gQKV, 256, 0, stream>>>(xb, wqkv + (size_t)l*196608, bqkv + l*768,
                                                      qkv, NTOK, D_MODEL, 768);
        flash_mfma_kernel<<<gAttn, 256, 0, stream>>>(qkv, ids, t0);
        gemm_ln_kernel<<<NTOK/64, 256, 0, stream>>>(t0, wto + (size_t)l*65536, bo + l*D_MODEL,
                                                    x, g1 + l*D_MODEL, be1 + l*D_MODEL,
                                                    x, xb, D_MODEL);
        gemm_bf16_kernel<1><<<gF1, 256, 0, stream>>>(xb, w1t + (size_t)l*262144, b1 + l*FFDIM,
                                                     hh, NTOK, D_MODEL, FFDIM);
        gemm_ln_kernel<<<NTOK/64, 256, 0, stream>>>(hh, w2t + (size_t)l*262144, b2 + l*D_MODEL,
                                                    x, g2 + l*D_MODEL, be2 + l*D_MODEL,
                                                    x, xb, FFDIM);
    }

    pool1_kernel<<<BB*16, 256, 0, stream>>>(x, ids, poolp);
    pool2_kernel<<<BB, 256, 0, stream>>>(poolp, ids, pooled);
    cls_kernel<<<1, 256, 0, stream>>>(pooled, Wc, bc, outp);
}

// Round 5
// 1314.024 us; speedup vs baseline: 9.3469x; 1.1398x over previous
//
#include <hip/hip_runtime.h>
#include <hip/hip_bf16.h>
#include <math.h>

#define D_MODEL 256
#define NHEADS 4
#define DK 64
#define NLAYERS 4
#define FFDIM 1024
#define BB 16
#define SS 2048
#define NTOK (BB*SS)

typedef __attribute__((ext_vector_type(8))) short bf16x8;
typedef __attribute__((ext_vector_type(4))) short s16x4;
typedef __attribute__((ext_vector_type(4))) float f32x4;

__device__ __forceinline__ short f2bf(float f) {
    __hip_bfloat16 h = __float2bfloat16(f);   // hardware RTNE cvt
    return *reinterpret_cast<short*>(&h);
}

// ---------------------------------------------------------------- embedding + posenc (dual write)
__global__ void embed_kernel(const int* __restrict__ ids, const float* __restrict__ emb,
                             float* __restrict__ x, short* __restrict__ xb) {
    int idx = blockIdx.x * 256 + threadIdx.x;
    int tok = idx >> 8;
    int d   = idx & 255;
    int s   = tok & (SS - 1);
    int id  = ids[tok];
    float e = emb[id * D_MODEL + d] * 16.0f;
    float i2 = (float)((d >> 1) << 1);
    float div = expf(i2 * (-9.210340371976184f / 256.0f));
    float ang = (float)s * div;
    float pe = (d & 1) ? cosf(ang) : sinf(ang);
    float val = e + pe;
    x[idx] = val;
    xb[idx] = f2bf(val);
}

// ---------------------------------------------------------------- weight prep: transpose + bf16
__global__ void wprep_kernel(const float* __restrict__ Wq, const float* __restrict__ Wk,
                             const float* __restrict__ Wv, const float* __restrict__ Wo,
                             const float* __restrict__ W1, const float* __restrict__ W2,
                             short* __restrict__ wqkv, short* __restrict__ wto,
                             short* __restrict__ w1t, short* __restrict__ w2t) {
    int wid = blockIdx.y, l = blockIdx.z, tile = blockIdx.x;
    int K = (wid == 5) ? 1024 : 256;
    int M = (wid == 4) ? 1024 : 256;
    int tiles = (K >> 6) * (M >> 6);
    if (tile >= tiles) return;
    const float* src; short* dst;
    switch (wid) {
        case 0: src = Wq; dst = wqkv + (size_t)l*196608;            break;
        case 1: src = Wk; dst = wqkv + (size_t)l*196608 + 65536;    break;
        case 2: src = Wv; dst = wqkv + (size_t)l*196608 + 131072;   break;
        case 3: src = Wo; dst = wto + (size_t)l*65536;              break;
        case 4: src = W1; dst = w1t + (size_t)l*262144;             break;
        default: src = W2; dst = w2t + (size_t)l*262144;            break;
    }
    src += (size_t)l * K * M;
    int tm = tile % (M >> 6), tk = tile / (M >> 6);

    __shared__ short t_s[64][68];
    int tid = threadIdx.x;
    #pragma unroll
    for (int u = 0; u < 16; ++u) {
        int e = tid + u * 256;
        int r = e >> 6, c = e & 63;
        t_s[c][r] = f2bf(src[(size_t)(tk*64 + r) * M + tm*64 + c]);
    }
    __syncthreads();
    #pragma unroll
    for (int u = 0; u < 4; ++u) {
        int e = tid + u * 256;
        int r = e >> 4, c4 = (e & 15) * 4;
        s16x4 v;
        v[0] = t_s[r][c4]; v[1] = t_s[r][c4+1]; v[2] = t_s[r][c4+2]; v[3] = t_s[r][c4+3];
        *(s16x4*)&dst[(size_t)(tm*64 + r) * K + tk*64 + c4] = v;
    }
}

// ---------------------------------------------------------------- fused QKV bias concat
__global__ void bprep_kernel(const float* __restrict__ bq, const float* __restrict__ bk,
                             const float* __restrict__ bv, float* __restrict__ bqkv) {
    int idx = blockIdx.x * 256 + threadIdx.x;
    if (idx >= NLAYERS * 768) return;
    int l = idx / 768, j = idx % 768;
    float v;
    if (j < 256) v = bq[l*256 + j];
    else if (j < 512) v = bk[l*256 + j - 256];
    else v = bv[l*256 + j - 512];
    bqkv[idx] = v;
}

// ---------------------------------------------------------------- bf16 MFMA GEMM (generic)
template<int RELU>
__global__ __launch_bounds__(256) void gemm_bf16_kernel(
        const short* __restrict__ A, const short* __restrict__ Wt,
        const float* __restrict__ bias, short* __restrict__ Cout,
        int N, int K, int M) {
    __shared__ short A_s[128][72];
    __shared__ short B_s[128][72];
    int tid = threadIdx.x;
    int w = tid >> 6, lane = tid & 63;
    int lr = lane & 15, lg = lane >> 4;
    int wr = w >> 1, wc = w & 1;
    int rowBase = blockIdx.x * 128;
    int colBase = blockIdx.y * 128;

    f32x4 acc[4][4];
    #pragma unroll
    for (int m = 0; m < 4; ++m)
        #pragma unroll
        for (int n = 0; n < 4; ++n)
            acc[m][n] = (f32x4){0.f, 0.f, 0.f, 0.f};

    for (int kt = 0; kt < K; kt += 64) {
        #pragma unroll
        for (int u = 0; u < 4; ++u) {
            int e = tid + u * 256;
            int r = e >> 3, c8 = (e & 7) * 8;
            *(bf16x8*)&A_s[r][c8] = *(const bf16x8*)(A + (size_t)(rowBase + r) * K + kt + c8);
        }
        #pragma unroll
        for (int u = 0; u < 4; ++u) {
            int e = tid + u * 256;
            int r = e >> 3, c8 = (e & 7) * 8;
            *(bf16x8*)&B_s[r][c8] = *(const bf16x8*)(Wt + (size_t)(colBase + r) * K + kt + c8);
        }
        __syncthreads();
        #pragma unroll
        for (int ks = 0; ks < 2; ++ks) {
            bf16x8 af[4], bfr[4];
            #pragma unroll
            for (int m = 0; m < 4; ++m)
                af[m] = *(const bf16x8*)&A_s[wr*64 + m*16 + lr][ks*32 + lg*8];
            #pragma unroll
            for (int n = 0; n < 4; ++n)
                bfr[n] = *(const bf16x8*)&B_s[wc*64 + n*16 + lr][ks*32 + lg*8];
            #pragma unroll
            for (int m = 0; m < 4; ++m)
                #pragma unroll
                for (int n = 0; n < 4; ++n)
                    acc[m][n] = __builtin_amdgcn_mfma_f32_16x16x32_bf16(af[m], bfr[n], acc[m][n], 0, 0, 0);
        }
        __syncthreads();
    }

    #pragma unroll
    for (int m = 0; m < 4; ++m) {
        int row = rowBase + wr*64 + m*16 + lg*4;
        #pragma unroll
        for (int n = 0; n < 4; ++n) {
            int col = colBase + wc*64 + n*16 + lr;
            float bv = bias[col];
            #pragma unroll
            for (int r = 0; r < 4; ++r) {
                float vv = acc[m][n][r] + bv;
                if (RELU) vv = fmaxf(vv, 0.0f);
                Cout[(size_t)(row + r) * M + col] = f2bf(vv);
            }
        }
    }
}

// ---------------------------------------------------------------- bf16 GEMM + residual + LN fused
__global__ __launch_bounds__(256) void gemm_ln_kernel(
        const short* __restrict__ A, const short* __restrict__ Wt,
        const float* __restrict__ bias, const float* __restrict__ resid,
        const float* __restrict__ g, const float* __restrict__ be,
        float* __restrict__ xf, short* __restrict__ xb, int K) {
    __shared__ short A_s[64][72];
    __shared__ short B_s[256][72];
    __shared__ float red_s[2][4][64];
    __shared__ float mu_s[64], rs_s[64];
    int tid = threadIdx.x;
    int w = tid >> 6, lane = tid & 63;
    int lr = lane & 15, lg = lane >> 4;
    int rowBase = blockIdx.x * 64;
    int colW = w * 64;

    f32x4 acc[4][4];
    #pragma unroll
    for (int m = 0; m < 4; ++m)
        #pragma unroll
        for (int n = 0; n < 4; ++n)
            acc[m][n] = (f32x4){0.f, 0.f, 0.f, 0.f};

    for (int kt = 0; kt < K; kt += 64) {
        #pragma unroll
        for (int u = 0; u < 2; ++u) {
            int e = tid + u * 256;
            int r = e >> 3, c8 = (e & 7) * 8;
            *(bf16x8*)&A_s[r][c8] = *(const bf16x8*)(A + (size_t)(rowBase + r) * K + kt + c8);
        }
        #pragma unroll
        for (int u = 0; u < 8; ++u) {
            int e = tid + u * 256;
            int r = e >> 3, c8 = (e & 7) * 8;
            *(bf16x8*)&B_s[r][c8] = *(const bf16x8*)(Wt + (size_t)r * K + kt + c8);
        }
        __syncthreads();
        #pragma unroll
        for (int ks = 0; ks < 2; ++ks) {
            bf16x8 af[4], bfr[4];
            #pragma unroll
            for (int m = 0; m < 4; ++m)
                af[m] = *(const bf16x8*)&A_s[m*16 + lr][ks*32 + lg*8];
            #pragma unroll
            for (int n = 0; n < 4; ++n)
                bfr[n] = *(const bf16x8*)&B_s[colW + n*16 + lr][ks*32 + lg*8];
            #pragma unroll
            for (int m = 0; m < 4; ++m)
                #pragma unroll
                for (int n = 0; n < 4; ++n)
                    acc[m][n] = __builtin_amdgcn_mfma_f32_16x16x32_bf16(af[m], bfr[n], acc[m][n], 0, 0, 0);
        }
        __syncthreads();
    }

    #pragma unroll
    for (int m = 0; m < 4; ++m) {
        #pragma unroll
        for (int n = 0; n < 4; ++n) {
            int col = colW + n*16 + lr;
            float bv = bias[col];
            #pragma unroll
            for (int r = 0; r < 4; ++r) {
                int row = rowBase + m*16 + lg*4 + r;
                acc[m][n][r] += bv + resid[(size_t)row * 256 + col];
            }
        }
    }
    #pragma unroll
    for (int m = 0; m < 4; ++m) {
        #pragma unroll
        for (int r = 0; r < 4; ++r) {
            float sum = acc[m][0][r] + acc[m][1][r] + acc[m][2][r] + acc[m][3][r];
            float sq  = acc[m][0][r]*acc[m][0][r] + acc[m][1][r]*acc[m][1][r]
                      + acc[m][2][r]*acc[m][2][r] + acc[m][3][r]*acc[m][3][r];
            #pragma unroll
            for (int off = 1; off < 16; off <<= 1) {
                sum += __shfl_xor(sum, off);
                sq  += __shfl_xor(sq, off);
            }
            if (lr == 0) {
                red_s[0][w][m*16 + lg*4 + r] = sum;
                red_s[1][w][m*16 + lg*4 + r] = sq;
            }
        }
    }
    __syncthreads();
    if (tid < 64) {
        float s = red_s[0][0][tid] + red_s[0][1][tid] + red_s[0][2][tid] + red_s[0][3][tid];
        float q = red_s[1][0][tid] + red_s[1][1][tid] + red_s[1][2][tid] + red_s[1][3][tid];
        float mu = s * (1.0f/256.0f);
        float var = q * (1.0f/256.0f) - mu*mu;
        mu_s[tid] = mu;
        rs_s[tid] = rsqrtf(var + 1e-5f);
    }
    __syncthreads();
    #pragma unroll
    for (int m = 0; m < 4; ++m) {
        #pragma unroll
        for (int n = 0; n < 4; ++n) {
            int col = colW + n*16 + lr;
            float gv = g[col], bev = be[col];
            #pragma unroll
            for (int r = 0; r < 4; ++r) {
                int rloc = m*16 + lg*4 + r;
                int row = rowBase + rloc;
                float o = (acc[m][n][r] - mu_s[rloc]) * rs_s[rloc] * gv + bev;
                xf[(size_t)row * 256 + col] = o;
                xb[(size_t)row * 256 + col] = f2bf(o);
            }
        }
    }
}

// ---------------------------------------------------------------- bf16 MFMA flash attention (swapped QK^T)
// 1D grid 1024 blocks (XCD-chunked); block = 4 waves; wave handles 32 q-rows (2 sets).
// S^T = mfma(A=K, B=Q): lane owns q-col lr; keys 16t+4lg+reg in regs -> lane-local softmax.
// O^T = mfma(A=V^T, B=P^T): lane owns q-col lr, d rows 16dt+4lg+reg.
__global__ __launch_bounds__(256) void flash_mfma_kernel(
        const short* __restrict__ qkv, const int* __restrict__ ids,
        short* __restrict__ out) {
    __shared__ short k_s[64][72];        // [key][d]
    __shared__ short vt_s[64][72];       // [d][swz(key)]
    __shared__ short p_s[4][32][72];     // per-wave P^T [q(2 sets)][swz(key)]
    __shared__ float madd_s[64];

    int bid = blockIdx.x;
    int work = (bid & 7) * 128 + (bid >> 3);     // XCD-chunked swizzle (1024 % 8 == 0)
    int qb = work & 15, h = (work >> 4) & 3, b = work >> 6;

    int tid = threadIdx.x;
    int w = tid >> 6, lane = tid & 63;
    int lr = lane & 15, lg = lane >> 4;
    int g = lr >> 2;                             // P t-block swizzle

    const short* qp = qkv + (size_t)b * SS * 768 + h * DK;
    const short* kp = qp + 256;
    const short* vp = qp + 512;

    bf16x8 qf[2][2];
    #pragma unroll
    for (int s = 0; s < 2; ++s) {
        int qrow = qb*128 + w*32 + s*16 + lr;
        #pragma unroll
        for (int ks = 0; ks < 2; ++ks)
            qf[s][ks] = *(const bf16x8*)(qp + (size_t)qrow * 768 + lg*8 + ks*32);
    }

    f32x4 o[2][4];
    float m_i[2] = {-1e30f, -1e30f}, l_i[2] = {0.0f, 0.0f};
    #pragma unroll
    for (int s = 0; s < 2; ++s)
        #pragma unroll
        for (int dt = 0; dt < 4; ++dt)
            o[s][dt] = (f32x4){0.f, 0.f, 0.f, 0.f};

    for (int kb = 0; kb < SS/64; ++kb) {
        __syncthreads();
        #pragma unroll
        for (int u = 0; u < 2; ++u) {
            int e = tid + u * 256;
            int r = e >> 3, c8 = (e & 7) * 8;
            *(bf16x8*)&k_s[r][c8] = *(const bf16x8*)(kp + (size_t)(kb*64 + r) * 768 + c8);
            bf16x8 vv = *(const bf16x8*)(vp + (size_t)(kb*64 + r) * 768 + c8);
            #pragma unroll
            for (int j = 0; j < 8; ++j) {
                int col = c8 + j;
                vt_s[col][((((r >> 3) ^ (col >> 3)) << 3) | (r & 7))] = vv[j];
            }
        }
        if (tid < 64)
            madd_s[tid] = (ids[b*SS + kb*64 + tid] != 0) ? 0.0f : -1e30f;
        __syncthreads();

        f32x4 madd4[4];
        #pragma unroll
        for (int t = 0; t < 4; ++t)
            madd4[t] = *(const f32x4*)&madd_s[16*t + 4*lg];

        // S^T = K @ Q^T  (shared K-frags across both q-sets)
        f32x4 sc[2][4];
        __builtin_amdgcn_s_setprio(1);
        #pragma unroll
        for (int t = 0; t < 4; ++t) {
            bf16x8 kf0 = *(const bf16x8*)&k_s[t*16 + lr][lg*8];
            bf16x8 kf1 = *(const bf16x8*)&k_s[t*16 + lr][lg*8 + 32];
            #pragma unroll
            for (int s = 0; s < 2; ++s) {
                f32x4 a = (f32x4){0.f, 0.f, 0.f, 0.f};
                a = __builtin_amdgcn_mfma_f32_16x16x32_bf16(kf0, qf[s][0], a, 0, 0, 0);
                a = __builtin_amdgcn_mfma_f32_16x16x32_bf16(kf1, qf[s][1], a, 0, 0, 0);
                sc[s][t] = a;
            }
        }
        __builtin_amdgcn_s_setprio(0);

        // lane-local online softmax (lane owns q-col lr; 16 keys in regs; 2 shuffles/reduce)
        #pragma unroll
        for (int s = 0; s < 2; ++s) {
            float sr[4][4];
            #pragma unroll
            for (int t = 0; t < 4; ++t)
                #pragma unroll
                for (int r = 0; r < 4; ++r)
                    sr[t][r] = sc[s][t][r] * 0.125f + madd4[t][r];

            float mx = sr[0][0];
            #pragma unroll
            for (int t = 0; t < 4; ++t)
                #pragma unroll
                for (int r = 0; r < 4; ++r)
                    mx = fmaxf(mx, sr[t][r]);
            mx = fmaxf(mx, __shfl_xor(mx, 16));
            mx = fmaxf(mx, __shfl_xor(mx, 32));

            float mnew = fmaxf(m_i[s], mx);
            float alpha = __expf(m_i[s] - mnew);
            float rsum = 0.0f;
            #pragma unroll
            for (int t = 0; t < 4; ++t)
                #pragma unroll
                for (int r = 0; r < 4; ++r) {
                    float p = (sr[t][r] < -5e29f) ? 0.0f : __expf(sr[t][r] - mnew);
                    sr[t][r] = p;
                    rsum += p;
                }
            rsum += __shfl_xor(rsum, 16);
            rsum += __shfl_xor(rsum, 32);
            l_i[s] = l_i[s] * alpha + rsum;
            m_i[s] = mnew;
            #pragma unroll
            for (int dt = 0; dt < 4; ++dt) o[s][dt] *= alpha;

            // P^T store: row q=lr, keys 16t+4lg+r at swizzled t-block (b64 stores)
            #pragma unroll
            for (int t = 0; t < 4; ++t) {
                s16x4 pw;
                #pragma unroll
                for (int r = 0; r < 4; ++r) pw[r] = f2bf(sr[t][r]);
                *(s16x4*)&p_s[w][s*16 + lr][16*(t ^ g) + 4*lg] = pw;
            }
        }
        // p_s is per-wave: no block barrier needed

        // O^T += V^T @ P^T
        bf16x8 pa[2][2];
        #pragma unroll
        for (int s = 0; s < 2; ++s)
            #pragma unroll
            for (int ks = 0; ks < 2; ++ks) {
                int t0 = 2*ks + (lg >> 1);
                pa[s][ks] = *(const bf16x8*)&p_s[w][s*16 + lr][16*(t0 ^ g) + 8*(lg & 1)];
            }
        __builtin_amdgcn_s_setprio(1);
        #pragma unroll
        for (int dt = 0; dt < 4; ++dt) {
            int col = dt*16 + lr;
            #pragma unroll
            for (int ks = 0; ks < 2; ++ks) {
                bf16x8 va = *(const bf16x8*)&vt_s[col][(((ks*4 + lg) ^ (col >> 3)) << 3)];
                #pragma unroll
                for (int s = 0; s < 2; ++s)
                    o[s][dt] = __builtin_amdgcn_mfma_f32_16x16x32_bf16(va, pa[s][ks], o[s][dt], 0, 0, 0);
            }
        }
        __builtin_amdgcn_s_setprio(0);
    }

    // epilogue: lane owns q-col lr; d = dt*16 + 4lg + reg (consecutive) -> b64 stores
    #pragma unroll
    for (int s = 0; s < 2; ++s) {
        float inv = 1.0f / l_i[s];
        int row = b*SS + qb*128 + w*32 + s*16 + lr;
        #pragma unroll
        for (int dt = 0; dt < 4; ++dt) {
            s16x4 ow;
            #pragma unroll
            for (int r = 0; r < 4; ++r) ow[r] = f2bf(o[s][dt][r] * inv);
            *(s16x4*)&out[(size_t)row * 256 + h*DK + dt*16 + 4*lg] = ow;
        }
    }
}

// ---------------------------------------------------------------- masked mean pool (2-stage)
__global__ void pool1_kernel(const float* __restrict__ x, const int* __restrict__ ids,
                             float* __restrict__ partial) {
    int b = blockIdx.x >> 4, chunk = blockIdx.x & 15;
    int d = threadIdx.x;
    float acc = 0.0f;
    int s0 = chunk * 128;
    for (int s = s0; s < s0 + 128; ++s) {
        if (ids[b*SS + s] != 0) acc += x[(size_t)(b*SS + s) * D_MODEL + d];
    }
    partial[(size_t)(b*16 + chunk) * D_MODEL + d] = acc;
}

__global__ void pool2_kernel(const float* __restrict__ partial, const int* __restrict__ ids,
                             float* __restrict__ pooled) {
    int b = blockIdx.x;
    int d = threadIdx.x;
    float acc = 0.0f;
    for (int c = 0; c < 16; ++c) acc += partial[(size_t)(b*16 + c) * D_MODEL + d];
    int cnt = 0;
    for (int s = threadIdx.x; s < SS; s += 256) cnt += (ids[b*SS + s] != 0);
    __shared__ int cs[256];
    cs[threadIdx.x] = cnt;
    __syncthreads();
    for (int off = 128; off > 0; off >>= 1) {
        if (threadIdx.x < off) cs[threadIdx.x] += cs[threadIdx.x + off];
        __syncthreads();
    }
    float total = (float)cs[0];
    pooled[b * D_MODEL + d] = acc / fmaxf(total, 1e-9f);
}

// ---------------------------------------------------------------- classifier 16x10
__global__ void cls_kernel(const float* __restrict__ pooled, const float* __restrict__ Wc,
                           const float* __restrict__ bc, float* __restrict__ outp) {
    int t = threadIdx.x;
    if (t >= BB * 10) return;
    int b = t / 10, c = t % 10;
    float acc = bc[c];
    for (int d = 0; d < D_MODEL; ++d)
        acc += pooled[b * D_MODEL + d] * Wc[d * 10 + c];
    outp[t] = acc;
}

// ---------------------------------------------------------------- launch
extern "C" void kernel_launch(void* const* d_in, const int* in_sizes, int n_in,
                              void* d_out, int out_size, void* d_ws, size_t ws_size,
                              hipStream_t stream) {
    const int*   ids = (const int*)  d_in[0];
    const float* emb = (const float*)d_in[1];
    const float* Wq  = (const float*)d_in[2];
    const float* bq  = (const float*)d_in[3];
    const float* Wk  = (const float*)d_in[4];
    const float* bk  = (const float*)d_in[5];
    const float* Wv  = (const float*)d_in[6];
    const float* bv  = (const float*)d_in[7];
    const float* Wo  = (const float*)d_in[8];
    const float* bo  = (const float*)d_in[9];
    const float* g1  = (const float*)d_in[10];
    const float* be1 = (const float*)d_in[11];
    const float* W1  = (const float*)d_in[12];
    const float* b1  = (const float*)d_in[13];
    const float* W2  = (const float*)d_in[14];
    const float* b2  = (const float*)d_in[15];
    const float* g2  = (const float*)d_in[16];
    const float* be2 = (const float*)d_in[17];
    const float* Wc  = (const float*)d_in[18];
    const float* bc  = (const float*)d_in[19];
    float* outp = (float*)d_out;

    const size_t TD = (size_t)NTOK * D_MODEL;     // 8.39M elems
    float* ws   = (float*)d_ws;
    float* x    = ws;                              // residual fp32
    short* sb   = (short*)(ws + TD);
    short* xb   = sb;                              // TD
    short* qkv  = sb + TD;                         // 3*TD  [tok][768]
    short* t0   = sb + 4*TD;                       // TD (attn out)
    short* hh   = qkv;                             // 4*TD (aliases qkv+t0, dead then)
    short* wqkv = sb + 5*TD;                       // L*768*256
    short* wto  = wqkv + (size_t)NLAYERS*196608;
    short* w1t  = wto  + (size_t)NLAYERS*65536;
    short* w2t  = w1t  + (size_t)NLAYERS*262144;
    float* bqkv = (float*)(w2t + (size_t)NLAYERS*262144);
    float* poolp = bqkv + NLAYERS*768;
    float* pooled = poolp + 65536;

    wprep_kernel<<<dim3(64, 6, NLAYERS), 256, 0, stream>>>(Wq, Wk, Wv, Wo, W1, W2,
                                                           wqkv, wto, w1t, w2t);
    bprep_kernel<<<12, 256, 0, stream>>>(bq, bk, bv, bqkv);
    embed_kernel<<<NTOK, 256, 0, stream>>>(ids, emb, x, xb);

    dim3 gQKV(NTOK/128, 768/128);      // (256, 6)
    dim3 gF1 (NTOK/128, FFDIM/128);    // (256, 8)

    for (int l = 0; l < NLAYERS; ++l) {
        gemm_bf16_kernel<0><<<gQKV, 256, 0, stream>>>(xb, wqkv + (size_t)l*196608, bqkv + l*768,
                                                      qkv, NTOK, D_MODEL, 768);
        flash_mfma_kernel<<<1024, 256, 0, stream>>>(qkv, ids, t0);
        gemm_ln_kernel<<<NTOK/64, 256, 0, stream>>>(t0, wto + (size_t)l*65536, bo + l*D_MODEL,
                                                    x, g1 + l*D_MODEL, be1 + l*D_MODEL,
                                                    x, xb, D_MODEL);
        gemm_bf16_kernel<1><<<gF1, 256, 0, stream>>>(xb, w1t + (size_t)l*262144, b1 + l*FFDIM,
                                                     hh, NTOK, D_MODEL, FFDIM);
        gemm_ln_kernel<<<NTOK/64, 256, 0, stream>>>(hh, w2t + (size_t)l*262144, b2 + l*D_MODEL,
                                                    x, g2 + l*D_MODEL, be2 + l*D_MODEL,
                                                    x, xb, FFDIM);
    }

    pool1_kernel<<<BB*16, 256, 0, stream>>>(x, ids, poolp);
    pool2_kernel<<<BB, 256, 0, stream>>>(poolp, ids, pooled);
    cls_kernel<<<1, 256, 0, stream>>>(pooled, Wc, bc, outp);
}

// Round 6
// 1139.321 us; speedup vs baseline: 10.7802x; 1.1533x over previous
//
#include <hip/hip_runtime.h>
#include <hip/hip_bf16.h>
#include <math.h>

#define D_MODEL 256
#define NHEADS 4
#define DK 64
#define NLAYERS 4
#define FFDIM 1024
#define BB 16
#define SS 2048
#define NTOK (BB*SS)

// Q pre-scale: 1/sqrt(64) * log2(e)  -> scores arrive in exp2 domain
#define QSCALE 0.18033688011112042f
#define MASKNEG -30000.0f

typedef __attribute__((ext_vector_type(8))) short bf16x8;
typedef __attribute__((ext_vector_type(4))) short s16x4;
typedef __attribute__((ext_vector_type(4))) float f32x4;

__device__ __forceinline__ short f2bf(float f) {
    __hip_bfloat16 h = __float2bfloat16(f);   // hardware RTNE cvt
    return *reinterpret_cast<short*>(&h);
}

// ---------------------------------------------------------------- embedding + posenc (dual write)
__global__ void embed_kernel(const int* __restrict__ ids, const float* __restrict__ emb,
                             float* __restrict__ x, short* __restrict__ xb) {
    int idx = blockIdx.x * 256 + threadIdx.x;
    int tok = idx >> 8;
    int d   = idx & 255;
    int s   = tok & (SS - 1);
    int id  = ids[tok];
    float e = emb[id * D_MODEL + d] * 16.0f;
    float i2 = (float)((d >> 1) << 1);
    float div = expf(i2 * (-9.210340371976184f / 256.0f));
    float ang = (float)s * div;
    float pe = (d & 1) ? cosf(ang) : sinf(ang);
    float val = e + pe;
    x[idx] = val;
    xb[idx] = f2bf(val);
}

// ---------------------------------------------------------------- weight prep: transpose + bf16
// wid 0 (Wq) is pre-scaled by QSCALE so QK^T lands in exp2 domain.
__global__ void wprep_kernel(const float* __restrict__ Wq, const float* __restrict__ Wk,
                             const float* __restrict__ Wv, const float* __restrict__ Wo,
                             const float* __restrict__ W1, const float* __restrict__ W2,
                             short* __restrict__ wqkv, short* __restrict__ wto,
                             short* __restrict__ w1t, short* __restrict__ w2t) {
    int wid = blockIdx.y, l = blockIdx.z, tile = blockIdx.x;
    int K = (wid == 5) ? 1024 : 256;
    int M = (wid == 4) ? 1024 : 256;
    int tiles = (K >> 6) * (M >> 6);
    if (tile >= tiles) return;
    const float* src; short* dst;
    float scale = (wid == 0) ? QSCALE : 1.0f;
    switch (wid) {
        case 0: src = Wq; dst = wqkv + (size_t)l*196608;            break;
        case 1: src = Wk; dst = wqkv + (size_t)l*196608 + 65536;    break;
        case 2: src = Wv; dst = wqkv + (size_t)l*196608 + 131072;   break;
        case 3: src = Wo; dst = wto + (size_t)l*65536;              break;
        case 4: src = W1; dst = w1t + (size_t)l*262144;             break;
        default: src = W2; dst = w2t + (size_t)l*262144;            break;
    }
    src += (size_t)l * K * M;
    int tm = tile % (M >> 6), tk = tile / (M >> 6);

    __shared__ short t_s[64][68];
    int tid = threadIdx.x;
    #pragma unroll
    for (int u = 0; u < 16; ++u) {
        int e = tid + u * 256;
        int r = e >> 6, c = e & 63;
        t_s[c][r] = f2bf(src[(size_t)(tk*64 + r) * M + tm*64 + c] * scale);
    }
    __syncthreads();
    #pragma unroll
    for (int u = 0; u < 4; ++u) {
        int e = tid + u * 256;
        int r = e >> 4, c4 = (e & 15) * 4;
        s16x4 v;
        v[0] = t_s[r][c4]; v[1] = t_s[r][c4+1]; v[2] = t_s[r][c4+2]; v[3] = t_s[r][c4+3];
        *(s16x4*)&dst[(size_t)(tm*64 + r) * K + tk*64 + c4] = v;
    }
}

// ---------------------------------------------------------------- fused QKV bias concat (bq scaled)
__global__ void bprep_kernel(const float* __restrict__ bq, const float* __restrict__ bk,
                             const float* __restrict__ bv, float* __restrict__ bqkv) {
    int idx = blockIdx.x * 256 + threadIdx.x;
    if (idx >= NLAYERS * 768) return;
    int l = idx / 768, j = idx % 768;
    float v;
    if (j < 256) v = bq[l*256 + j] * QSCALE;
    else if (j < 512) v = bk[l*256 + j - 256];
    else v = bv[l*256 + j - 512];
    bqkv[idx] = v;
}

// ---------------------------------------------------------------- bf16 MFMA GEMM (generic)
template<int RELU>
__global__ __launch_bounds__(256) void gemm_bf16_kernel(
        const short* __restrict__ A, const short* __restrict__ Wt,
        const float* __restrict__ bias, short* __restrict__ Cout,
        int N, int K, int M) {
    __shared__ short A_s[128][72];
    __shared__ short B_s[128][72];
    int tid = threadIdx.x;
    int w = tid >> 6, lane = tid & 63;
    int lr = lane & 15, lg = lane >> 4;
    int wr = w >> 1, wc = w & 1;
    int rowBase = blockIdx.x * 128;
    int colBase = blockIdx.y * 128;

    f32x4 acc[4][4];
    #pragma unroll
    for (int m = 0; m < 4; ++m)
        #pragma unroll
        for (int n = 0; n < 4; ++n)
            acc[m][n] = (f32x4){0.f, 0.f, 0.f, 0.f};

    for (int kt = 0; kt < K; kt += 64) {
        #pragma unroll
        for (int u = 0; u < 4; ++u) {
            int e = tid + u * 256;
            int r = e >> 3, c8 = (e & 7) * 8;
            *(bf16x8*)&A_s[r][c8] = *(const bf16x8*)(A + (size_t)(rowBase + r) * K + kt + c8);
        }
        #pragma unroll
        for (int u = 0; u < 4; ++u) {
            int e = tid + u * 256;
            int r = e >> 3, c8 = (e & 7) * 8;
            *(bf16x8*)&B_s[r][c8] = *(const bf16x8*)(Wt + (size_t)(colBase + r) * K + kt + c8);
        }
        __syncthreads();
        #pragma unroll
        for (int ks = 0; ks < 2; ++ks) {
            bf16x8 af[4], bfr[4];
            #pragma unroll
            for (int m = 0; m < 4; ++m)
                af[m] = *(const bf16x8*)&A_s[wr*64 + m*16 + lr][ks*32 + lg*8];
            #pragma unroll
            for (int n = 0; n < 4; ++n)
                bfr[n] = *(const bf16x8*)&B_s[wc*64 + n*16 + lr][ks*32 + lg*8];
            #pragma unroll
            for (int m = 0; m < 4; ++m)
                #pragma unroll
                for (int n = 0; n < 4; ++n)
                    acc[m][n] = __builtin_amdgcn_mfma_f32_16x16x32_bf16(af[m], bfr[n], acc[m][n], 0, 0, 0);
        }
        __syncthreads();
    }

    #pragma unroll
    for (int m = 0; m < 4; ++m) {
        int row = rowBase + wr*64 + m*16 + lg*4;
        #pragma unroll
        for (int n = 0; n < 4; ++n) {
            int col = colBase + wc*64 + n*16 + lr;
            float bv = bias[col];
            #pragma unroll
            for (int r = 0; r < 4; ++r) {
                float vv = acc[m][n][r] + bv;
                if (RELU) vv = fmaxf(vv, 0.0f);
                Cout[(size_t)(row + r) * M + col] = f2bf(vv);
            }
        }
    }
}

// ---------------------------------------------------------------- bf16 GEMM + residual + LN fused
__global__ __launch_bounds__(256) void gemm_ln_kernel(
        const short* __restrict__ A, const short* __restrict__ Wt,
        const float* __restrict__ bias, const float* __restrict__ resid,
        const float* __restrict__ g, const float* __restrict__ be,
        float* __restrict__ xf, short* __restrict__ xb, int K) {
    __shared__ short A_s[64][72];
    __shared__ short B_s[256][72];
    __shared__ float red_s[2][4][64];
    __shared__ float mu_s[64], rs_s[64];
    int tid = threadIdx.x;
    int w = tid >> 6, lane = tid & 63;
    int lr = lane & 15, lg = lane >> 4;
    int rowBase = blockIdx.x * 64;
    int colW = w * 64;

    f32x4 acc[4][4];
    #pragma unroll
    for (int m = 0; m < 4; ++m)
        #pragma unroll
        for (int n = 0; n < 4; ++n)
            acc[m][n] = (f32x4){0.f, 0.f, 0.f, 0.f};

    for (int kt = 0; kt < K; kt += 64) {
        #pragma unroll
        for (int u = 0; u < 2; ++u) {
            int e = tid + u * 256;
            int r = e >> 3, c8 = (e & 7) * 8;
            *(bf16x8*)&A_s[r][c8] = *(const bf16x8*)(A + (size_t)(rowBase + r) * K + kt + c8);
        }
        #pragma unroll
        for (int u = 0; u < 8; ++u) {
            int e = tid + u * 256;
            int r = e >> 3, c8 = (e & 7) * 8;
            *(bf16x8*)&B_s[r][c8] = *(const bf16x8*)(Wt + (size_t)r * K + kt + c8);
        }
        __syncthreads();
        #pragma unroll
        for (int ks = 0; ks < 2; ++ks) {
            bf16x8 af[4], bfr[4];
            #pragma unroll
            for (int m = 0; m < 4; ++m)
                af[m] = *(const bf16x8*)&A_s[m*16 + lr][ks*32 + lg*8];
            #pragma unroll
            for (int n = 0; n < 4; ++n)
                bfr[n] = *(const bf16x8*)&B_s[colW + n*16 + lr][ks*32 + lg*8];
            #pragma unroll
            for (int m = 0; m < 4; ++m)
                #pragma unroll
                for (int n = 0; n < 4; ++n)
                    acc[m][n] = __builtin_amdgcn_mfma_f32_16x16x32_bf16(af[m], bfr[n], acc[m][n], 0, 0, 0);
        }
        __syncthreads();
    }

    #pragma unroll
    for (int m = 0; m < 4; ++m) {
        #pragma unroll
        for (int n = 0; n < 4; ++n) {
            int col = colW + n*16 + lr;
            float bv = bias[col];
            #pragma unroll
            for (int r = 0; r < 4; ++r) {
                int row = rowBase + m*16 + lg*4 + r;
                acc[m][n][r] += bv + resid[(size_t)row * 256 + col];
            }
        }
    }
    #pragma unroll
    for (int m = 0; m < 4; ++m) {
        #pragma unroll
        for (int r = 0; r < 4; ++r) {
            float sum = acc[m][0][r] + acc[m][1][r] + acc[m][2][r] + acc[m][3][r];
            float sq  = acc[m][0][r]*acc[m][0][r] + acc[m][1][r]*acc[m][1][r]
                      + acc[m][2][r]*acc[m][2][r] + acc[m][3][r]*acc[m][3][r];
            #pragma unroll
            for (int off = 1; off < 16; off <<= 1) {
                sum += __shfl_xor(sum, off);
                sq  += __shfl_xor(sq, off);
            }
            if (lr == 0) {
                red_s[0][w][m*16 + lg*4 + r] = sum;
                red_s[1][w][m*16 + lg*4 + r] = sq;
            }
        }
    }
    __syncthreads();
    if (tid < 64) {
        float s = red_s[0][0][tid] + red_s[0][1][tid] + red_s[0][2][tid] + red_s[0][3][tid];
        float q = red_s[1][0][tid] + red_s[1][1][tid] + red_s[1][2][tid] + red_s[1][3][tid];
        float mu = s * (1.0f/256.0f);
        float var = q * (1.0f/256.0f) - mu*mu;
        mu_s[tid] = mu;
        rs_s[tid] = rsqrtf(var + 1e-5f);
    }
    __syncthreads();
    #pragma unroll
    for (int m = 0; m < 4; ++m) {
        #pragma unroll
        for (int n = 0; n < 4; ++n) {
            int col = colW + n*16 + lr;
            float gv = g[col], bev = be[col];
            #pragma unroll
            for (int r = 0; r < 4; ++r) {
                int rloc = m*16 + lg*4 + r;
                int row = rowBase + rloc;
                float o = (acc[m][n][r] - mu_s[rloc]) * rs_s[rloc] * gv + bev;
                xf[(size_t)row * 256 + col] = o;
                xb[(size_t)row * 256 + col] = f2bf(o);
            }
        }
    }
}

// ---------------------------------------------------------------- bf16 MFMA flash attention
// Swapped QK^T (S^T = K@Q^T, exp2-domain scores, mask via MFMA C-input), sequential
// q-sets sharing one p_s buffer, T14 async-stage (next tile in regs during compute).
__global__ __launch_bounds__(256) void flash_mfma_kernel(
        const short* __restrict__ qkv, const int* __restrict__ ids,
        short* __restrict__ out) {
    __shared__ short k_s[64][72];        // [key][d]
    __shared__ short vt_s[64][72];       // [d][swz(key)]
    __shared__ short p_s[4][16][72];     // per-wave P^T [q][swz(key)] (shared by both sets)
    __shared__ float madd_s[64];

    int bid = blockIdx.x;
    int work = (bid & 7) * 128 + (bid >> 3);     // XCD-chunked swizzle
    int qb = work & 15, h = (work >> 4) & 3, b = work >> 6;

    int tid = threadIdx.x;
    int w = tid >> 6, lane = tid & 63;
    int lr = lane & 15, lg = lane >> 4;
    int g = lr >> 2;                             // P t-block swizzle

    const short* qp = qkv + (size_t)b * SS * 768 + h * DK;
    const short* kp = qp + 256;
    const short* vp = qp + 512;

    bf16x8 qf[2][2];
    #pragma unroll
    for (int s = 0; s < 2; ++s) {
        int qrow = qb*128 + w*32 + s*16 + lr;
        #pragma unroll
        for (int ks = 0; ks < 2; ++ks)
            qf[s][ks] = *(const bf16x8*)(qp + (size_t)qrow * 768 + lg*8 + ks*32);
    }

    f32x4 o[2][4];
    float m_i[2] = {-1e30f, -1e30f}, l_i[2] = {0.0f, 0.0f};
    #pragma unroll
    for (int s = 0; s < 2; ++s)
        #pragma unroll
        for (int dt = 0; dt < 4; ++dt)
            o[s][dt] = (f32x4){0.f, 0.f, 0.f, 0.f};

    // prologue: stage tile 0 into registers
    bf16x8 kr[2], vr[2];
    int idv = 1;
    #pragma unroll
    for (int u = 0; u < 2; ++u) {
        int e = tid + u * 256;
        int r = e >> 3, c8 = (e & 7) * 8;
        kr[u] = *(const bf16x8*)(kp + (size_t)r * 768 + c8);
        vr[u] = *(const bf16x8*)(vp + (size_t)r * 768 + c8);
    }
    if (tid < 64) idv = ids[b*SS + tid];

    for (int kb = 0; kb < SS/64; ++kb) {
        __syncthreads();   // all waves done reading k_s/vt_s from prev tile
        // write staged regs -> LDS
        #pragma unroll
        for (int u = 0; u < 2; ++u) {
            int e = tid + u * 256;
            int r = e >> 3, c8 = (e & 7) * 8;
            *(bf16x8*)&k_s[r][c8] = kr[u];
            #pragma unroll
            for (int j = 0; j < 8; ++j) {
                int col = c8 + j;
                vt_s[col][((((r >> 3) ^ (col >> 3)) << 3) | (r & 7))] = vr[u][j];
            }
        }
        if (tid < 64)
            madd_s[tid] = (idv != 0) ? 0.0f : MASKNEG;
        // issue next-tile loads (land during compute below)
        if (kb + 1 < SS/64) {
            #pragma unroll
            for (int u = 0; u < 2; ++u) {
                int e = tid + u * 256;
                int r = e >> 3, c8 = (e & 7) * 8;
                kr[u] = *(const bf16x8*)(kp + (size_t)((kb+1)*64 + r) * 768 + c8);
                vr[u] = *(const bf16x8*)(vp + (size_t)((kb+1)*64 + r) * 768 + c8);
            }
            if (tid < 64) idv = ids[b*SS + (kb+1)*64 + tid];
        }
        __syncthreads();

        f32x4 madd4[4];
        #pragma unroll
        for (int t = 0; t < 4; ++t)
            madd4[t] = *(const f32x4*)&madd_s[16*t + 4*lg];

        // S^T = K @ Q^T + mask (C-input); shared K-frags across both q-sets
        f32x4 sc[2][4];
        __builtin_amdgcn_s_setprio(1);
        #pragma unroll
        for (int t = 0; t < 4; ++t) {
            bf16x8 kf0 = *(const bf16x8*)&k_s[t*16 + lr][lg*8];
            bf16x8 kf1 = *(const bf16x8*)&k_s[t*16 + lr][lg*8 + 32];
            #pragma unroll
            for (int s = 0; s < 2; ++s) {
                f32x4 a = __builtin_amdgcn_mfma_f32_16x16x32_bf16(kf0, qf[s][0], madd4[t], 0, 0, 0);
                a = __builtin_amdgcn_mfma_f32_16x16x32_bf16(kf1, qf[s][1], a, 0, 0, 0);
                sc[s][t] = a;
            }
        }
        __builtin_amdgcn_s_setprio(0);

        // per-set: lane-local softmax (exp2 domain) + PV, sequential (shared p_s)
        #pragma unroll
        for (int s = 0; s < 2; ++s) {
            float mx = sc[s][0][0];
            #pragma unroll
            for (int t = 0; t < 4; ++t)
                #pragma unroll
                for (int r = 0; r < 4; ++r)
                    mx = fmaxf(mx, sc[s][t][r]);
            mx = fmaxf(mx, __shfl_xor(mx, 16));
            mx = fmaxf(mx, __shfl_xor(mx, 32));

            if (!__all(mx <= m_i[s])) {          // exact skip-rescale
                float mnew = fmaxf(m_i[s], mx);
                float alpha = __builtin_amdgcn_exp2f(m_i[s] - mnew);
                l_i[s] *= alpha;
                #pragma unroll
                for (int dt = 0; dt < 4; ++dt) o[s][dt] *= alpha;
                m_i[s] = mnew;
            }

            float rsum = 0.0f;
            float pv[4][4];
            #pragma unroll
            for (int t = 0; t < 4; ++t)
                #pragma unroll
                for (int r = 0; r < 4; ++r) {
                    float p = __builtin_amdgcn_exp2f(sc[s][t][r] - m_i[s]);
                    pv[t][r] = p;
                    rsum += p;
                }
            rsum += __shfl_xor(rsum, 16);
            rsum += __shfl_xor(rsum, 32);
            l_i[s] += rsum;

            #pragma unroll
            for (int t = 0; t < 4; ++t) {
                s16x4 pw;
                #pragma unroll
                for (int r = 0; r < 4; ++r) pw[r] = f2bf(pv[t][r]);
                *(s16x4*)&p_s[w][lr][16*(t ^ g) + 4*lg] = pw;
            }

            // O^T += V^T @ P^T
            bf16x8 pa[2];
            #pragma unroll
            for (int ks = 0; ks < 2; ++ks) {
                int t0 = 2*ks + (lg >> 1);
                pa[ks] = *(const bf16x8*)&p_s[w][lr][16*(t0 ^ g) + 8*(lg & 1)];
            }
            __builtin_amdgcn_s_setprio(1);
            #pragma unroll
            for (int dt = 0; dt < 4; ++dt) {
                int col = dt*16 + lr;
                #pragma unroll
                for (int ks = 0; ks < 2; ++ks) {
                    bf16x8 va = *(const bf16x8*)&vt_s[col][(((ks*4 + lg) ^ (col >> 3)) << 3)];
                    o[s][dt] = __builtin_amdgcn_mfma_f32_16x16x32_bf16(va, pa[ks], o[s][dt], 0, 0, 0);
                }
            }
            __builtin_amdgcn_s_setprio(0);
        }
    }

    // epilogue
    #pragma unroll
    for (int s = 0; s < 2; ++s) {
        float inv = 1.0f / l_i[s];
        int row = b*SS + qb*128 + w*32 + s*16 + lr;
        #pragma unroll
        for (int dt = 0; dt < 4; ++dt) {
            s16x4 ow;
            #pragma unroll
            for (int r = 0; r < 4; ++r) ow[r] = f2bf(o[s][dt][r] * inv);
            *(s16x4*)&out[(size_t)row * 256 + h*DK + dt*16 + 4*lg] = ow;
        }
    }
}

// ---------------------------------------------------------------- masked mean pool (2-stage)
__global__ void pool1_kernel(const float* __restrict__ x, const int* __restrict__ ids,
                             float* __restrict__ partial) {
    int b = blockIdx.x >> 4, chunk = blockIdx.x & 15;
    int d = threadIdx.x;
    float acc = 0.0f;
    int s0 = chunk * 128;
    for (int s = s0; s < s0 + 128; ++s) {
        if (ids[b*SS + s] != 0) acc += x[(size_t)(b*SS + s) * D_MODEL + d];
    }
    partial[(size_t)(b*16 + chunk) * D_MODEL + d] = acc;
}

__global__ void pool2_kernel(const float* __restrict__ partial, const int* __restrict__ ids,
                             float* __restrict__ pooled) {
    int b = blockIdx.x;
    int d = threadIdx.x;
    float acc = 0.0f;
    for (int c = 0; c < 16; ++c) acc += partial[(size_t)(b*16 + c) * D_MODEL + d];
    int cnt = 0;
    for (int s = threadIdx.x; s < SS; s += 256) cnt += (ids[b*SS + s] != 0);
    __shared__ int cs[256];
    cs[threadIdx.x] = cnt;
    __syncthreads();
    for (int off = 128; off > 0; off >>= 1) {
        if (threadIdx.x < off) cs[threadIdx.x] += cs[threadIdx.x + off];
        __syncthreads();
    }
    float total = (float)cs[0];
    pooled[b * D_MODEL + d] = acc / fmaxf(total, 1e-9f);
}

// ---------------------------------------------------------------- classifier 16x10
__global__ void cls_kernel(const float* __restrict__ pooled, const float* __restrict__ Wc,
                           const float* __restrict__ bc, float* __restrict__ outp) {
    int t = threadIdx.x;
    if (t >= BB * 10) return;
    int b = t / 10, c = t % 10;
    float acc = bc[c];
    for (int d = 0; d < D_MODEL; ++d)
        acc += pooled[b * D_MODEL + d] * Wc[d * 10 + c];
    outp[t] = acc;
}

// ---------------------------------------------------------------- launch
extern "C" void kernel_launch(void* const* d_in, const int* in_sizes, int n_in,
                              void* d_out, int out_size, void* d_ws, size_t ws_size,
                              hipStream_t stream) {
    const int*   ids = (const int*)  d_in[0];
    const float* emb = (const float*)d_in[1];
    const float* Wq  = (const float*)d_in[2];
    const float* bq  = (const float*)d_in[3];
    const float* Wk  = (const float*)d_in[4];
    const float* bk  = (const float*)d_in[5];
    const float* Wv  = (const float*)d_in[6];
    const float* bv  = (const float*)d_in[7];
    const float* Wo  = (const float*)d_in[8];
    const float* bo  = (const float*)d_in[9];
    const float* g1  = (const float*)d_in[10];
    const float* be1 = (const float*)d_in[11];
    const float* W1  = (const float*)d_in[12];
    const float* b1  = (const float*)d_in[13];
    const float* W2  = (const float*)d_in[14];
    const float* b2  = (const float*)d_in[15];
    const float* g2  = (const float*)d_in[16];
    const float* be2 = (const float*)d_in[17];
    const float* Wc  = (const float*)d_in[18];
    const float* bc  = (const float*)d_in[19];
    float* outp = (float*)d_out;

    const size_t TD = (size_t)NTOK * D_MODEL;     // 8.39M elems
    float* ws   = (float*)d_ws;
    float* x    = ws;                              // residual fp32
    short* sb   = (short*)(ws + TD);
    short* xb   = sb;                              // TD
    short* qkv  = sb + TD;                         // 3*TD  [tok][768]
    short* t0   = sb + 4*TD;                       // TD (attn out)
    short* hh   = qkv;                             // 4*TD (aliases qkv+t0, dead then)
    short* wqkv = sb + 5*TD;                       // L*768*256
    short* wto  = wqkv + (size_t)NLAYERS*196608;
    short* w1t  = wto  + (size_t)NLAYERS*65536;
    short* w2t  = w1t  + (size_t)NLAYERS*262144;
    float* bqkv = (float*)(w2t + (size_t)NLAYERS*262144);
    float* poolp = bqkv + NLAYERS*768;
    float* pooled = poolp + 65536;

    wprep_kernel<<<dim3(64, 6, NLAYERS), 256, 0, stream>>>(Wq, Wk, Wv, Wo, W1, W2,
                                                           wqkv, wto, w1t, w2t);
    bprep_kernel<<<12, 256, 0, stream>>>(bq, bk, bv, bqkv);
    embed_kernel<<<NTOK, 256, 0, stream>>>(ids, emb, x, xb);

    dim3 gQKV(NTOK/128, 768/128);      // (256, 6)
    dim3 gF1 (NTOK/128, FFDIM/128);    // (256, 8)

    for (int l = 0; l < NLAYERS; ++l) {
        gemm_bf16_kernel<0><<<gQKV, 256, 0, stream>>>(xb, wqkv + (size_t)l*196608, bqkv + l*768,
                                                      qkv, NTOK, D_MODEL, 768);
        flash_mfma_kernel<<<1024, 256, 0, stream>>>(qkv, ids, t0);
        gemm_ln_kernel<<<NTOK/64, 256, 0, stream>>>(t0, wto + (size_t)l*65536, bo + l*D_MODEL,
                                                    x, g1 + l*D_MODEL, be1 + l*D_MODEL,
                                                    x, xb, D_MODEL);
        gemm_bf16_kernel<1><<<gF1, 256, 0, stream>>>(xb, w1t + (size_t)l*262144, b1 + l*FFDIM,
                                                     hh, NTOK, D_MODEL, FFDIM);
        gemm_ln_kernel<<<NTOK/64, 256, 0, stream>>>(hh, w2t + (size_t)l*262144, b2 + l*D_MODEL,
                                                    x, g2 + l*D_MODEL, be2 + l*D_MODEL,
                                                    x, xb, FFDIM);
    }

    pool1_kernel<<<BB*16, 256, 0, stream>>>(x, ids, poolp);
    pool2_kernel<<<BB, 256, 0, stream>>>(poolp, ids, pooled);
    cls_kernel<<<1, 256, 0, stream>>>(pooled, Wc, bc, outp);
}

// Round 7
// 1084.867 us; speedup vs baseline: 11.3213x; 1.0502x over previous
//
#include <hip/hip_runtime.h>
#include <hip/hip_bf16.h>
#include <math.h>

#define D_MODEL 256
#define NHEADS 4
#define DK 64
#define NLAYERS 4
#define FFDIM 1024
#define BB 16
#define SS 2048
#define NTOK (BB*SS)

// Q pre-scale: 1/sqrt(64) * log2(e)  -> scores arrive in exp2 domain
#define QSCALE 0.18033688011112042f
#define MASKNEG -30000.0f

typedef __attribute__((ext_vector_type(8))) short bf16x8;
typedef __attribute__((ext_vector_type(4))) short s16x4;
typedef __attribute__((ext_vector_type(4))) float f32x4;

__device__ __forceinline__ short f2bf(float f) {
    __hip_bfloat16 h = __float2bfloat16(f);   // hardware RTNE cvt
    return *reinterpret_cast<short*>(&h);
}

// ---------------------------------------------------------------- embedding + posenc (dual write)
__global__ void embed_kernel(const int* __restrict__ ids, const float* __restrict__ emb,
                             float* __restrict__ x, short* __restrict__ xb) {
    int idx = blockIdx.x * 256 + threadIdx.x;
    int tok = idx >> 8;
    int d   = idx & 255;
    int s   = tok & (SS - 1);
    int id  = ids[tok];
    float e = emb[id * D_MODEL + d] * 16.0f;
    float i2 = (float)((d >> 1) << 1);
    float div = expf(i2 * (-9.210340371976184f / 256.0f));
    float ang = (float)s * div;
    float pe = (d & 1) ? cosf(ang) : sinf(ang);
    float val = e + pe;
    x[idx] = val;
    xb[idx] = f2bf(val);
}

// ---------------------------------------------------------------- weight prep: transpose + bf16
// wid 0 (Wq) is pre-scaled by QSCALE so QK^T lands in exp2 domain.
__global__ void wprep_kernel(const float* __restrict__ Wq, const float* __restrict__ Wk,
                             const float* __restrict__ Wv, const float* __restrict__ Wo,
                             const float* __restrict__ W1, const float* __restrict__ W2,
                             short* __restrict__ wqkv, short* __restrict__ wto,
                             short* __restrict__ w1t, short* __restrict__ w2t) {
    int wid = blockIdx.y, l = blockIdx.z, tile = blockIdx.x;
    int K = (wid == 5) ? 1024 : 256;
    int M = (wid == 4) ? 1024 : 256;
    int tiles = (K >> 6) * (M >> 6);
    if (tile >= tiles) return;
    const float* src; short* dst;
    float scale = (wid == 0) ? QSCALE : 1.0f;
    switch (wid) {
        case 0: src = Wq; dst = wqkv + (size_t)l*196608;            break;
        case 1: src = Wk; dst = wqkv + (size_t)l*196608 + 65536;    break;
        case 2: src = Wv; dst = wqkv + (size_t)l*196608 + 131072;   break;
        case 3: src = Wo; dst = wto + (size_t)l*65536;              break;
        case 4: src = W1; dst = w1t + (size_t)l*262144;             break;
        default: src = W2; dst = w2t + (size_t)l*262144;            break;
    }
    src += (size_t)l * K * M;
    int tm = tile % (M >> 6), tk = tile / (M >> 6);

    __shared__ short t_s[64][68];
    int tid = threadIdx.x;
    #pragma unroll
    for (int u = 0; u < 16; ++u) {
        int e = tid + u * 256;
        int r = e >> 6, c = e & 63;
        t_s[c][r] = f2bf(src[(size_t)(tk*64 + r) * M + tm*64 + c] * scale);
    }
    __syncthreads();
    #pragma unroll
    for (int u = 0; u < 4; ++u) {
        int e = tid + u * 256;
        int r = e >> 4, c4 = (e & 15) * 4;
        s16x4 v;
        v[0] = t_s[r][c4]; v[1] = t_s[r][c4+1]; v[2] = t_s[r][c4+2]; v[3] = t_s[r][c4+3];
        *(s16x4*)&dst[(size_t)(tm*64 + r) * K + tk*64 + c4] = v;
    }
}

// ---------------------------------------------------------------- fused QKV bias concat (bq scaled)
__global__ void bprep_kernel(const float* __restrict__ bq, const float* __restrict__ bk,
                             const float* __restrict__ bv, float* __restrict__ bqkv) {
    int idx = blockIdx.x * 256 + threadIdx.x;
    if (idx >= NLAYERS * 768) return;
    int l = idx / 768, j = idx % 768;
    float v;
    if (j < 256) v = bq[l*256 + j] * QSCALE;
    else if (j < 512) v = bk[l*256 + j - 256];
    else v = bv[l*256 + j - 512];
    bqkv[idx] = v;
}

// ---------------------------------------------------------------- bf16 MFMA GEMM (generic)
// VSPLIT: cols >= 512 (the V part of fused QKV) are written TRANSPOSED to
// vt[(b*NHEADS+h)*DK + d][s] — 4 consecutive tokens per lane = one b64 store.
template<int RELU, int VSPLIT>
__global__ __launch_bounds__(256) void gemm_bf16_kernel(
        const short* __restrict__ A, const short* __restrict__ Wt,
        const float* __restrict__ bias, short* __restrict__ Cout,
        short* __restrict__ vt, int N, int K, int M) {
    __shared__ short A_s[128][72];
    __shared__ short B_s[128][72];
    int tid = threadIdx.x;
    int w = tid >> 6, lane = tid & 63;
    int lr = lane & 15, lg = lane >> 4;
    int wr = w >> 1, wc = w & 1;
    int rowBase = blockIdx.x * 128;
    int colBase = blockIdx.y * 128;

    f32x4 acc[4][4];
    #pragma unroll
    for (int m = 0; m < 4; ++m)
        #pragma unroll
        for (int n = 0; n < 4; ++n)
            acc[m][n] = (f32x4){0.f, 0.f, 0.f, 0.f};

    for (int kt = 0; kt < K; kt += 64) {
        #pragma unroll
        for (int u = 0; u < 4; ++u) {
            int e = tid + u * 256;
            int r = e >> 3, c8 = (e & 7) * 8;
            *(bf16x8*)&A_s[r][c8] = *(const bf16x8*)(A + (size_t)(rowBase + r) * K + kt + c8);
        }
        #pragma unroll
        for (int u = 0; u < 4; ++u) {
            int e = tid + u * 256;
            int r = e >> 3, c8 = (e & 7) * 8;
            *(bf16x8*)&B_s[r][c8] = *(const bf16x8*)(Wt + (size_t)(colBase + r) * K + kt + c8);
        }
        __syncthreads();
        #pragma unroll
        for (int ks = 0; ks < 2; ++ks) {
            bf16x8 af[4], bfr[4];
            #pragma unroll
            for (int m = 0; m < 4; ++m)
                af[m] = *(const bf16x8*)&A_s[wr*64 + m*16 + lr][ks*32 + lg*8];
            #pragma unroll
            for (int n = 0; n < 4; ++n)
                bfr[n] = *(const bf16x8*)&B_s[wc*64 + n*16 + lr][ks*32 + lg*8];
            #pragma unroll
            for (int m = 0; m < 4; ++m)
                #pragma unroll
                for (int n = 0; n < 4; ++n)
                    acc[m][n] = __builtin_amdgcn_mfma_f32_16x16x32_bf16(af[m], bfr[n], acc[m][n], 0, 0, 0);
        }
        __syncthreads();
    }

    #pragma unroll
    for (int m = 0; m < 4; ++m) {
        int row = rowBase + wr*64 + m*16 + lg*4;
        #pragma unroll
        for (int n = 0; n < 4; ++n) {
            int col = colBase + wc*64 + n*16 + lr;
            float bv = bias[col];
            if (VSPLIT && col >= 512) {
                int hh = (col - 512) >> 6, dl = (col - 512) & 63;
                int bb = row >> 11, s0 = row & 2047;   // 4 consecutive tokens, same b
                s16x4 ow;
                #pragma unroll
                for (int r = 0; r < 4; ++r) ow[r] = f2bf(acc[m][n][r] + bv);
                *(s16x4*)&vt[((size_t)(bb * NHEADS + hh) * DK + dl) * SS + s0] = ow;
            } else {
                #pragma unroll
                for (int r = 0; r < 4; ++r) {
                    float vv = acc[m][n][r] + bv;
                    if (RELU) vv = fmaxf(vv, 0.0f);
                    Cout[(size_t)(row + r) * M + col] = f2bf(vv);
                }
            }
        }
    }
}

// ---------------------------------------------------------------- bf16 GEMM + residual + LN fused
__global__ __launch_bounds__(256) void gemm_ln_kernel(
        const short* __restrict__ A, const short* __restrict__ Wt,
        const float* __restrict__ bias, const float* __restrict__ resid,
        const float* __restrict__ g, const float* __restrict__ be,
        float* __restrict__ xf, short* __restrict__ xb, int K) {
    __shared__ short A_s[64][72];
    __shared__ short B_s[256][72];
    __shared__ float red_s[2][4][64];
    __shared__ float mu_s[64], rs_s[64];
    int tid = threadIdx.x;
    int w = tid >> 6, lane = tid & 63;
    int lr = lane & 15, lg = lane >> 4;
    int rowBase = blockIdx.x * 64;
    int colW = w * 64;

    f32x4 acc[4][4];
    #pragma unroll
    for (int m = 0; m < 4; ++m)
        #pragma unroll
        for (int n = 0; n < 4; ++n)
            acc[m][n] = (f32x4){0.f, 0.f, 0.f, 0.f};

    for (int kt = 0; kt < K; kt += 64) {
        #pragma unroll
        for (int u = 0; u < 2; ++u) {
            int e = tid + u * 256;
            int r = e >> 3, c8 = (e & 7) * 8;
            *(bf16x8*)&A_s[r][c8] = *(const bf16x8*)(A + (size_t)(rowBase + r) * K + kt + c8);
        }
        #pragma unroll
        for (int u = 0; u < 8; ++u) {
            int e = tid + u * 256;
            int r = e >> 3, c8 = (e & 7) * 8;
            *(bf16x8*)&B_s[r][c8] = *(const bf16x8*)(Wt + (size_t)r * K + kt + c8);
        }
        __syncthreads();
        #pragma unroll
        for (int ks = 0; ks < 2; ++ks) {
            bf16x8 af[4], bfr[4];
            #pragma unroll
            for (int m = 0; m < 4; ++m)
                af[m] = *(const bf16x8*)&A_s[m*16 + lr][ks*32 + lg*8];
            #pragma unroll
            for (int n = 0; n < 4; ++n)
                bfr[n] = *(const bf16x8*)&B_s[colW + n*16 + lr][ks*32 + lg*8];
            #pragma unroll
            for (int m = 0; m < 4; ++m)
                #pragma unroll
                for (int n = 0; n < 4; ++n)
                    acc[m][n] = __builtin_amdgcn_mfma_f32_16x16x32_bf16(af[m], bfr[n], acc[m][n], 0, 0, 0);
        }
        __syncthreads();
    }

    #pragma unroll
    for (int m = 0; m < 4; ++m) {
        #pragma unroll
        for (int n = 0; n < 4; ++n) {
            int col = colW + n*16 + lr;
            float bv = bias[col];
            #pragma unroll
            for (int r = 0; r < 4; ++r) {
                int row = rowBase + m*16 + lg*4 + r;
                acc[m][n][r] += bv + resid[(size_t)row * 256 + col];
            }
        }
    }
    #pragma unroll
    for (int m = 0; m < 4; ++m) {
        #pragma unroll
        for (int r = 0; r < 4; ++r) {
            float sum = acc[m][0][r] + acc[m][1][r] + acc[m][2][r] + acc[m][3][r];
            float sq  = acc[m][0][r]*acc[m][0][r] + acc[m][1][r]*acc[m][1][r]
                      + acc[m][2][r]*acc[m][2][r] + acc[m][3][r]*acc[m][3][r];
            #pragma unroll
            for (int off = 1; off < 16; off <<= 1) {
                sum += __shfl_xor(sum, off);
                sq  += __shfl_xor(sq, off);
            }
            if (lr == 0) {
                red_s[0][w][m*16 + lg*4 + r] = sum;
                red_s[1][w][m*16 + lg*4 + r] = sq;
            }
        }
    }
    __syncthreads();
    if (tid < 64) {
        float s = red_s[0][0][tid] + red_s[0][1][tid] + red_s[0][2][tid] + red_s[0][3][tid];
        float q = red_s[1][0][tid] + red_s[1][1][tid] + red_s[1][2][tid] + red_s[1][3][tid];
        float mu = s * (1.0f/256.0f);
        float var = q * (1.0f/256.0f) - mu*mu;
        mu_s[tid] = mu;
        rs_s[tid] = rsqrtf(var + 1e-5f);
    }
    __syncthreads();
    #pragma unroll
    for (int m = 0; m < 4; ++m) {
        #pragma unroll
        for (int n = 0; n < 4; ++n) {
            int col = colW + n*16 + lr;
            float gv = g[col], bev = be[col];
            #pragma unroll
            for (int r = 0; r < 4; ++r) {
                int rloc = m*16 + lg*4 + r;
                int row = rowBase + rloc;
                float o = (acc[m][n][r] - mu_s[rloc]) * rs_s[rloc] * gv + bev;
                xf[(size_t)row * 256 + col] = o;
                xb[(size_t)row * 256 + col] = f2bf(o);
            }
        }
    }
}

// ---------------------------------------------------------------- bf16 MFMA flash attention
// V arrives pre-transposed in vt_g[(b*H+h)*DK + d][s] -> linear b128 LDS staging,
// conflict-free b128 fragment reads. PV dt-outer so each va read feeds both q-sets.
__global__ __launch_bounds__(256) void flash_mfma_kernel(
        const short* __restrict__ qkv, const short* __restrict__ vt_g,
        const int* __restrict__ ids, short* __restrict__ out) {
    __shared__ short k_s[64][72];        // [key][d]
    __shared__ short vt_s[64][72];       // [d][key]   (V^T, linear)
    __shared__ short p_s[4][32][72];     // per-wave P^T, both q-sets
    __shared__ float madd_s[64];

    int bid = blockIdx.x;
    int work = (bid & 7) * 128 + (bid >> 3);     // XCD-chunked swizzle
    int qb = work & 15, h = (work >> 4) & 3, b = work >> 6;

    int tid = threadIdx.x;
    int w = tid >> 6, lane = tid & 63;
    int lr = lane & 15, lg = lane >> 4;
    int g = lr >> 2;                             // P t-block swizzle

    const short* qp = qkv + (size_t)b * SS * 768 + h * DK;
    const short* kp = qp + 256;
    const short* vtp = vt_g + (size_t)(b * NHEADS + h) * DK * SS;

    bf16x8 qf[2][2];
    #pragma unroll
    for (int s = 0; s < 2; ++s) {
        int qrow = qb*128 + w*32 + s*16 + lr;
        #pragma unroll
        for (int ks = 0; ks < 2; ++ks)
            qf[s][ks] = *(const bf16x8*)(qp + (size_t)qrow * 768 + lg*8 + ks*32);
    }

    f32x4 o[2][4];
    float m_i[2] = {-1e30f, -1e30f}, l_i[2] = {0.0f, 0.0f};
    #pragma unroll
    for (int s = 0; s < 2; ++s)
        #pragma unroll
        for (int dt = 0; dt < 4; ++dt)
            o[s][dt] = (f32x4){0.f, 0.f, 0.f, 0.f};

    int r0 = tid >> 3, c8 = (tid & 7) * 8;       // staging coords (u adds 32 to row)

    // prologue: stage tile 0 into registers
    bf16x8 kr[2], vr[2];
    int idv = 1;
    #pragma unroll
    for (int u = 0; u < 2; ++u) {
        kr[u] = *(const bf16x8*)(kp + (size_t)(r0 + u*32) * 768 + c8);
        vr[u] = *(const bf16x8*)(vtp + (size_t)(r0 + u*32) * SS + c8);
    }
    if (tid < 64) idv = ids[b*SS + tid];

    for (int kb = 0; kb < SS/64; ++kb) {
        __syncthreads();   // all waves done reading k_s/vt_s from prev tile
        #pragma unroll
        for (int u = 0; u < 2; ++u) {
            *(bf16x8*)&k_s[r0 + u*32][c8] = kr[u];
            *(bf16x8*)&vt_s[r0 + u*32][c8] = vr[u];
        }
        if (tid < 64)
            madd_s[tid] = (idv != 0) ? 0.0f : MASKNEG;
        // issue next-tile loads (land during compute below)
        if (kb + 1 < SS/64) {
            #pragma unroll
            for (int u = 0; u < 2; ++u) {
                kr[u] = *(const bf16x8*)(kp + (size_t)((kb+1)*64 + r0 + u*32) * 768 + c8);
                vr[u] = *(const bf16x8*)(vtp + (size_t)(r0 + u*32) * SS + (kb+1)*64 + c8);
            }
            if (tid < 64) idv = ids[b*SS + (kb+1)*64 + tid];
        }
        __syncthreads();

        f32x4 madd4[4];
        #pragma unroll
        for (int t = 0; t < 4; ++t)
            madd4[t] = *(const f32x4*)&madd_s[16*t + 4*lg];

        // S^T = K @ Q^T + mask (C-input); K-frags shared across both q-sets
        f32x4 sc[2][4];
        __builtin_amdgcn_s_setprio(1);
        #pragma unroll
        for (int t = 0; t < 4; ++t) {
            bf16x8 kf0 = *(const bf16x8*)&k_s[t*16 + lr][lg*8];
            bf16x8 kf1 = *(const bf16x8*)&k_s[t*16 + lr][lg*8 + 32];
            #pragma unroll
            for (int s = 0; s < 2; ++s) {
                f32x4 a = __builtin_amdgcn_mfma_f32_16x16x32_bf16(kf0, qf[s][0], madd4[t], 0, 0, 0);
                a = __builtin_amdgcn_mfma_f32_16x16x32_bf16(kf1, qf[s][1], a, 0, 0, 0);
                sc[s][t] = a;
            }
        }
        __builtin_amdgcn_s_setprio(0);

        // lane-local online softmax (exp2 domain), both sets -> p_s
        #pragma unroll
        for (int s = 0; s < 2; ++s) {
            float mx = sc[s][0][0];
            #pragma unroll
            for (int t = 0; t < 4; ++t)
                #pragma unroll
                for (int r = 0; r < 4; ++r)
                    mx = fmaxf(mx, sc[s][t][r]);
            mx = fmaxf(mx, __shfl_xor(mx, 16));
            mx = fmaxf(mx, __shfl_xor(mx, 32));

            if (!__all(mx <= m_i[s])) {          // exact skip-rescale
                float mnew = fmaxf(m_i[s], mx);
                float alpha = __builtin_amdgcn_exp2f(m_i[s] - mnew);
                l_i[s] *= alpha;
                #pragma unroll
                for (int dt = 0; dt < 4; ++dt) o[s][dt] *= alpha;
                m_i[s] = mnew;
            }

            float rsum = 0.0f;
            float pv[4][4];
            #pragma unroll
            for (int t = 0; t < 4; ++t)
                #pragma unroll
                for (int r = 0; r < 4; ++r) {
                    float p = __builtin_amdgcn_exp2f(sc[s][t][r] - m_i[s]);
                    pv[t][r] = p;
                    rsum += p;
                }
            rsum += __shfl_xor(rsum, 16);
            rsum += __shfl_xor(rsum, 32);
            l_i[s] += rsum;

            #pragma unroll
            for (int t = 0; t < 4; ++t) {
                s16x4 pw;
                #pragma unroll
                for (int r = 0; r < 4; ++r) pw[r] = f2bf(pv[t][r]);
                *(s16x4*)&p_s[w][s*16 + lr][16*(t ^ g) + 4*lg] = pw;
            }
        }
        // p_s is per-wave: no block barrier needed

        // O^T += V^T @ P^T ; va read once per (dt,ks), feeds both sets
        bf16x8 pa[2][2];
        #pragma unroll
        for (int s = 0; s < 2; ++s)
            #pragma unroll
            for (int ks = 0; ks < 2; ++ks) {
                int t0 = 2*ks + (lg >> 1);
                pa[s][ks] = *(const bf16x8*)&p_s[w][s*16 + lr][16*(t0 ^ g) + 8*(lg & 1)];
            }
        __builtin_amdgcn_s_setprio(1);
        #pragma unroll
        for (int dt = 0; dt < 4; ++dt) {
            #pragma unroll
            for (int ks = 0; ks < 2; ++ks) {
                bf16x8 va = *(const bf16x8*)&vt_s[dt*16 + lr][ks*32 + lg*8];
                o[0][dt] = __builtin_amdgcn_mfma_f32_16x16x32_bf16(va, pa[0][ks], o[0][dt], 0, 0, 0);
                o[1][dt] = __builtin_amdgcn_mfma_f32_16x16x32_bf16(va, pa[1][ks], o[1][dt], 0, 0, 0);
            }
        }
        __builtin_amdgcn_s_setprio(0);
    }

    // epilogue: lane owns q-col lr; d = dt*16 + 4lg + reg (consecutive) -> b64 stores
    #pragma unroll
    for (int s = 0; s < 2; ++s) {
        float inv = 1.0f / l_i[s];
        int row = b*SS + qb*128 + w*32 + s*16 + lr;
        #pragma unroll
        for (int dt = 0; dt < 4; ++dt) {
            s16x4 ow;
            #pragma unroll
            for (int r = 0; r < 4; ++r) ow[r] = f2bf(o[s][dt][r] * inv);
            *(s16x4*)&out[(size_t)row * 256 + h*DK + dt*16 + 4*lg] = ow;
        }
    }
}

// ---------------------------------------------------------------- masked mean pool (2-stage)
__global__ void pool1_kernel(const float* __restrict__ x, const int* __restrict__ ids,
                             float* __restrict__ partial) {
    int b = blockIdx.x >> 4, chunk = blockIdx.x & 15;
    int d = threadIdx.x;
    float acc = 0.0f;
    int s0 = chunk * 128;
    for (int s = s0; s < s0 + 128; ++s) {
        if (ids[b*SS + s] != 0) acc += x[(size_t)(b*SS + s) * D_MODEL + d];
    }
    partial[(size_t)(b*16 + chunk) * D_MODEL + d] = acc;
}

__global__ void pool2_kernel(const float* __restrict__ partial, const int* __restrict__ ids,
                             float* __restrict__ pooled) {
    int b = blockIdx.x;
    int d = threadIdx.x;
    float acc = 0.0f;
    for (int c = 0; c < 16; ++c) acc += partial[(size_t)(b*16 + c) * D_MODEL + d];
    int cnt = 0;
    for (int s = threadIdx.x; s < SS; s += 256) cnt += (ids[b*SS + s] != 0);
    __shared__ int cs[256];
    cs[threadIdx.x] = cnt;
    __syncthreads();
    for (int off = 128; off > 0; off >>= 1) {
        if (threadIdx.x < off) cs[threadIdx.x] += cs[threadIdx.x + off];
        __syncthreads();
    }
    float total = (float)cs[0];
    pooled[b * D_MODEL + d] = acc / fmaxf(total, 1e-9f);
}

// ---------------------------------------------------------------- classifier 16x10
__global__ void cls_kernel(const float* __restrict__ pooled, const float* __restrict__ Wc,
                           const float* __restrict__ bc, float* __restrict__ outp) {
    int t = threadIdx.x;
    if (t >= BB * 10) return;
    int b = t / 10, c = t % 10;
    float acc = bc[c];
    for (int d = 0; d < D_MODEL; ++d)
        acc += pooled[b * D_MODEL + d] * Wc[d * 10 + c];
    outp[t] = acc;
}

// ---------------------------------------------------------------- launch
extern "C" void kernel_launch(void* const* d_in, const int* in_sizes, int n_in,
                              void* d_out, int out_size, void* d_ws, size_t ws_size,
                              hipStream_t stream) {
    const int*   ids = (const int*)  d_in[0];
    const float* emb = (const float*)d_in[1];
    const float* Wq  = (const float*)d_in[2];
    const float* bq  = (const float*)d_in[3];
    const float* Wk  = (const float*)d_in[4];
    const float* bk  = (const float*)d_in[5];
    const float* Wv  = (const float*)d_in[6];
    const float* bv  = (const float*)d_in[7];
    const float* Wo  = (const float*)d_in[8];
    const float* bo  = (const float*)d_in[9];
    const float* g1  = (const float*)d_in[10];
    const float* be1 = (const float*)d_in[11];
    const float* W1  = (const float*)d_in[12];
    const float* b1  = (const float*)d_in[13];
    const float* W2  = (const float*)d_in[14];
    const float* b2  = (const float*)d_in[15];
    const float* g2  = (const float*)d_in[16];
    const float* be2 = (const float*)d_in[17];
    const float* Wc  = (const float*)d_in[18];
    const float* bc  = (const float*)d_in[19];
    float* outp = (float*)d_out;

    const size_t TD = (size_t)NTOK * D_MODEL;     // 8.39M elems
    float* ws   = (float*)d_ws;
    float* x    = ws;                              // residual fp32
    short* sb   = (short*)(ws + TD);
    short* xb   = sb;                              // TD
    short* qkv  = sb + TD;                         // 3*TD  [tok][768]  (V region unused)
    short* t0   = sb + 4*TD;                       // TD (attn out)
    short* vt_g = sb + 5*TD;                       // TD  V^T [(b*H+h)*DK + d][s]
    short* hh   = qkv;                             // 4*TD (aliases qkv+t0, dead then)
    short* wqkv = sb + 6*TD;                       // L*768*256
    short* wto  = wqkv + (size_t)NLAYERS*196608;
    short* w1t  = wto  + (size_t)NLAYERS*65536;
    short* w2t  = w1t  + (size_t)NLAYERS*262144;
    float* bqkv = (float*)(w2t + (size_t)NLAYERS*262144);
    float* poolp = bqkv + NLAYERS*768;
    float* pooled = poolp + 65536;

    wprep_kernel<<<dim3(64, 6, NLAYERS), 256, 0, stream>>>(Wq, Wk, Wv, Wo, W1, W2,
                                                           wqkv, wto, w1t, w2t);
    bprep_kernel<<<12, 256, 0, stream>>>(bq, bk, bv, bqkv);
    embed_kernel<<<NTOK, 256, 0, stream>>>(ids, emb, x, xb);

    dim3 gQKV(NTOK/128, 768/128);      // (256, 6)
    dim3 gF1 (NTOK/128, FFDIM/128);    // (256, 8)

    for (int l = 0; l < NLAYERS; ++l) {
        gemm_bf16_kernel<0,1><<<gQKV, 256, 0, stream>>>(xb, wqkv + (size_t)l*196608, bqkv + l*768,
                                                        qkv, vt_g, NTOK, D_MODEL, 768);
        flash_mfma_kernel<<<1024, 256, 0, stream>>>(qkv, vt_g, ids, t0);
        gemm_ln_kernel<<<NTOK/64, 256, 0, stream>>>(t0, wto + (size_t)l*65536, bo + l*D_MODEL,
                                                    x, g1 + l*D_MODEL, be1 + l*D_MODEL,
                                                    x, xb, D_MODEL);
        gemm_bf16_kernel<1,0><<<gF1, 256, 0, stream>>>(xb, w1t + (size_t)l*262144, b1 + l*FFDIM,
                                                       hh, nullptr, NTOK, D_MODEL, FFDIM);
        gemm_ln_kernel<<<NTOK/64, 256, 0, stream>>>(hh, w2t + (size_t)l*262144, b2 + l*D_MODEL,
                                                    x, g2 + l*D_MODEL, be2 + l*D_MODEL,
                                                    x, xb, FFDIM);
    }

    pool1_kernel<<<BB*16, 256, 0, stream>>>(x, ids, poolp);
    pool2_kernel<<<BB, 256, 0, stream>>>(poolp, ids, pooled);
    cls_kernel<<<1, 256, 0, stream>>>(pooled, Wc, bc, outp);
}